// Round 1
// baseline (206.447 us; speedup 1.0000x reference)
//
#include <hip/hip_runtime.h>
#include <stdint.h>

// ---------------------------------------------------------------------------
// Fused MHA forward: B=2, S=2048, E=1024, H=16, D=64, fp32 in/out,
// bf16 MFMA compute internally (threshold is 2% of max|ref| -> ample).
// ---------------------------------------------------------------------------

typedef __bf16 bf16_t;
typedef __bf16 bf16x8 __attribute__((ext_vector_type(8)));
typedef __bf16 bf16x4 __attribute__((ext_vector_type(4)));
typedef float f32x4 __attribute__((ext_vector_type(4)));

#define S_LEN 2048

__device__ __forceinline__ void load_lds16(const void* g, void* l) {
  // async global->LDS, 16B per lane; LDS dest is wave-uniform base + lane*16
  __builtin_amdgcn_global_load_lds((__attribute__((address_space(1))) void*)g,
                                   (__attribute__((address_space(3))) void*)l,
                                   16, 0, 0);
}

__device__ __forceinline__ f32x4 mfma16(bf16x8 a, bf16x8 b, f32x4 c) {
  return __builtin_amdgcn_mfma_f32_16x16x32_bf16(a, b, c, 0, 0, 0);
}

// ---------------- fp32 -> bf16 convert (vectorized) ----------------
__global__ void cvt_bf16(const float* __restrict__ in, bf16_t* __restrict__ out, int n) {
  int i = (blockIdx.x * blockDim.x + threadIdx.x) * 4;
  if (i >= n) return;
  float4 v = *reinterpret_cast<const float4*>(in + i);
  bf16x4 o;
  o[0] = (bf16_t)v.x; o[1] = (bf16_t)v.y; o[2] = (bf16_t)v.z; o[3] = (bf16_t)v.w;
  *reinterpret_cast<bf16x4*>(out + i) = o;
}

// ---------------- common 128x128 / BK=32 GEMM core (K=1024) ----------------
// A [M][1024] bf16 row-major, Bt [N][1024] bf16 row-major (i.e. B^T).
// 4 waves 2x2, each wave 64x64 out = 4x4 MFMA tiles. Linear LDS (m97-style).
__device__ __forceinline__ void gemm_main(const bf16_t* __restrict__ ga,
                                          const bf16_t* __restrict__ gb,
                                          bf16_t* As, bf16_t* Bs,
                                          int t, int wr, int wc, int lg, int lr,
                                          f32x4 (&acc)[4][4]) {
  for (int k0 = 0; k0 < 1024; k0 += 32) {
    load_lds16(ga + k0,          As + t * 8);
    load_lds16(ga + 65536 + k0,  As + 2048 + t * 8);   // +64 rows
    load_lds16(gb + k0,          Bs + t * 8);
    load_lds16(gb + 65536 + k0,  Bs + 2048 + t * 8);
    __syncthreads();
    bf16x8 af[4], bfr[4];
#pragma unroll
    for (int mt = 0; mt < 4; ++mt)
      af[mt] = *reinterpret_cast<const bf16x8*>(As + ((wr * 64 + mt * 16 + lr) << 5) + lg * 8);
#pragma unroll
    for (int nt = 0; nt < 4; ++nt)
      bfr[nt] = *reinterpret_cast<const bf16x8*>(Bs + ((wc * 64 + nt * 16 + lr) << 5) + lg * 8);
#pragma unroll
    for (int mt = 0; mt < 4; ++mt)
#pragma unroll
      for (int nt = 0; nt < 4; ++nt)
        acc[mt][nt] = mfma16(af[mt], bfr[nt], acc[mt][nt]);
    __syncthreads();
  }
}

// ---------------- GEMM1: QKV projection + bias + per-head LN ----------------
// A = xb [4096][1024]; Bt = Wb [3072][1024] (rows: Wq | Wk | Wv).
// Q/K: LN over D=64 then bf16 -> Qb/Kb [bh][s][d]. V: bf16 -> Vt [bh][d][s].
__launch_bounds__(256, 2)
__global__ void gemm_qkv_ln(const bf16_t* __restrict__ A, const bf16_t* __restrict__ Bt,
                            const float* __restrict__ bq, const float* __restrict__ bk,
                            const float* __restrict__ bv,
                            const float* __restrict__ qnw, const float* __restrict__ qnb,
                            const float* __restrict__ knw, const float* __restrict__ knb,
                            bf16_t* __restrict__ Qb, bf16_t* __restrict__ Kb,
                            bf16_t* __restrict__ Vt) {
  __shared__ alignas(16) bf16_t As[128 * 32];
  __shared__ alignas(16) bf16_t Bs[128 * 32];
  const int t = threadIdx.x;
  const int bm = blockIdx.y, bn = blockIdx.x;
  const int w = t >> 6, lane = t & 63;
  const int wr = w >> 1, wc = w & 1;
  const int lg = lane >> 4, lr = lane & 15;

  f32x4 acc[4][4] = {};
  const int srow = t >> 2;
  const int scol = (t & 3) << 3;
  const bf16_t* ga = A + ((size_t)(bm * 128 + srow) << 10) + scol;
  const bf16_t* gb = Bt + ((size_t)(bn * 128 + srow) << 10) + scol;
  gemm_main(ga, gb, As, Bs, t, wr, wc, lg, lr, acc);

  const int nbase = bn * 128 + wc * 64;   // multiple of 64 => one head per wave
  const int region = nbase >> 10;         // 0=Q 1=K 2=V
  const int h = (nbase & 1023) >> 6;

  if (region == 2) {
#pragma unroll
    for (int mt = 0; mt < 4; ++mt)
#pragma unroll
      for (int r = 0; r < 4; ++r) {
        const int gm = bm * 128 + wr * 64 + mt * 16 + lg * 4 + r;
        const int b = gm >> 11, s = gm & 2047;
#pragma unroll
        for (int nt = 0; nt < 4; ++nt) {
          const int d = nt * 16 + lr;
          float val = acc[mt][nt][r] + bv[h * 64 + d];
          Vt[((size_t)((b * 16 + h) * 64 + d) << 11) + s] = (bf16_t)val;
        }
      }
  } else {
    const float* bias = region ? bk : bq;
    const float* lw = region ? knw : qnw;
    const float* lb = region ? knb : qnb;
    bf16_t* Outp = region ? Kb : Qb;
#pragma unroll
    for (int mt = 0; mt < 4; ++mt)
#pragma unroll
      for (int r = 0; r < 4; ++r) {
        const int gm = bm * 128 + wr * 64 + mt * 16 + lg * 4 + r;
        const int b = gm >> 11, s = gm & 2047;
        float vv[4], sum = 0.f, sumsq = 0.f;
#pragma unroll
        for (int nt = 0; nt < 4; ++nt) {
          const int d = nt * 16 + lr;
          vv[nt] = acc[mt][nt][r] + bias[h * 64 + d];
          sum += vv[nt];
          sumsq += vv[nt] * vv[nt];
        }
        // reduce across the 16-lane group holding this q-row (xor masks 1,2,4,8)
#pragma unroll
        for (int mk = 1; mk < 16; mk <<= 1) {
          sum += __shfl_xor(sum, mk);
          sumsq += __shfl_xor(sumsq, mk);
        }
        const float mean = sum * (1.f / 64.f);
        const float var = sumsq * (1.f / 64.f) - mean * mean;
        const float rstd = rsqrtf(var + 1e-5f);
        const size_t rowoff = ((size_t)((b * 16 + h) * 2048 + s)) << 6;
#pragma unroll
        for (int nt = 0; nt < 4; ++nt) {
          const int d = nt * 16 + lr;
          float y = (vv[nt] - mean) * rstd * lw[d] + lb[d];
          Outp[rowoff + d] = (bf16_t)y;
        }
      }
  }
}

// ---------------- GEMM2: output projection -> fp32 d_out ----------------
__launch_bounds__(256, 2)
__global__ void gemm_out(const bf16_t* __restrict__ A, const bf16_t* __restrict__ Bt,
                         const float* __restrict__ bo, float* __restrict__ dout) {
  __shared__ alignas(16) bf16_t As[128 * 32];
  __shared__ alignas(16) bf16_t Bs[128 * 32];
  const int t = threadIdx.x;
  const int bm = blockIdx.y, bn = blockIdx.x;
  const int w = t >> 6, lane = t & 63;
  const int wr = w >> 1, wc = w & 1;
  const int lg = lane >> 4, lr = lane & 15;

  f32x4 acc[4][4] = {};
  const int srow = t >> 2;
  const int scol = (t & 3) << 3;
  const bf16_t* ga = A + ((size_t)(bm * 128 + srow) << 10) + scol;
  const bf16_t* gb = Bt + ((size_t)(bn * 128 + srow) << 10) + scol;
  gemm_main(ga, gb, As, Bs, t, wr, wc, lg, lr, acc);

#pragma unroll
  for (int mt = 0; mt < 4; ++mt)
#pragma unroll
    for (int r = 0; r < 4; ++r) {
      const int gm = bm * 128 + wr * 64 + mt * 16 + lg * 4 + r;
#pragma unroll
      for (int nt = 0; nt < 4; ++nt) {
        const int gn = bn * 128 + wc * 64 + nt * 16 + lr;
        dout[((size_t)gm << 10) + gn] = acc[mt][nt][r] + bo[gn];
      }
    }
}

// ---------------- flash attention ----------------
// grid (32 qtiles, 32 bh), 4 waves, wave owns 16 q-rows. KV tile = 64 keys.
// K/V LDS rows are 128B -> XOR-swizzle chunk ^= (row&7), applied on the
// GLOBAL source during global_load_lds staging (linear LDS dest) and on reads.
__launch_bounds__(256, 2)
__global__ void attn_kernel(const bf16_t* __restrict__ Qb, const bf16_t* __restrict__ Kb,
                            const bf16_t* __restrict__ Vt, bf16_t* __restrict__ Og) {
  __shared__ alignas(16) bf16_t Ks[64 * 64];
  __shared__ alignas(16) bf16_t Vs[64 * 64];
  __shared__ alignas(16) bf16_t Ps[4][16 * 64];

  const int t = threadIdx.x;
  const int w = t >> 6, lane = t & 63;
  const int lg = lane >> 4, lr = lane & 15;
  const int bh = blockIdx.y;
  const int q0 = blockIdx.x * 64 + w * 16;

  // Q fragments (A-side): lane holds Q[q0 + (l&15)][(l>>4)*8 + c*32 ..+8]
  bf16x8 qf0, qf1;
  {
    const bf16_t* qp = Qb + (((size_t)bh * S_LEN + q0 + lr) << 6) + lg * 8;
    qf0 = *reinterpret_cast<const bf16x8*>(qp);
    qf1 = *reinterpret_cast<const bf16x8*>(qp + 32);
  }

  f32x4 oacc[4] = {};
  float mst[4] = {-1e30f, -1e30f, -1e30f, -1e30f};
  float lst[4] = {0.f, 0.f, 0.f, 0.f};
  const float sc = 0.125f * 1.44269504f;  // 1/sqrt(D) * log2(e)

  const int srow = t >> 3;  // 0..31
  const int scc = t & 7;    // 16B chunk within 128B row

  for (int j = 0; j < 32; ++j) {
    {  // stage K tile [64][64] and V^T tile [64 d][64 keys], swizzled source
      const bf16_t* kb = Kb + (((size_t)bh * S_LEN + j * 64) << 6);
      const bf16_t* vb = Vt + ((size_t)bh << 17) + j * 64;
      const int r0 = srow, r1 = srow + 32;
      const int c0 = (scc ^ (r0 & 7)) << 3;
      const int c1 = (scc ^ (r1 & 7)) << 3;
      load_lds16(kb + (r0 << 6) + c0, Ks + t * 8);
      load_lds16(kb + (r1 << 6) + c1, Ks + 2048 + t * 8);
      load_lds16(vb + r0 * S_LEN + c0, Vs + t * 8);
      load_lds16(vb + r1 * S_LEN + c1, Vs + 2048 + t * 8);
    }
    __syncthreads();

    // S = Q K^T : score[q=(lg*4+r)][key=kt*16+lr]
    f32x4 sacc[4];
#pragma unroll
    for (int kt = 0; kt < 4; ++kt) {
      const int row = kt * 16 + lr;
      const int sw = row & 7;
      bf16x8 kv0 = *reinterpret_cast<const bf16x8*>(Ks + (row << 6) + ((lg ^ sw) << 3));
      bf16x8 kv1 = *reinterpret_cast<const bf16x8*>(Ks + (row << 6) + (((lg + 4) ^ sw) << 3));
      f32x4 z = {};
      z = mfma16(qf0, kv0, z);
      z = mfma16(qf1, kv1, z);
      sacc[kt] = z;
    }

    // online softmax (log2 domain)
    float pm[4];
#pragma unroll
    for (int r = 0; r < 4; ++r)
      pm[r] = fmaxf(fmaxf(sacc[0][r], sacc[1][r]), fmaxf(sacc[2][r], sacc[3][r]));
#pragma unroll
    for (int mk = 1; mk < 16; mk <<= 1)
#pragma unroll
      for (int r = 0; r < 4; ++r) pm[r] = fmaxf(pm[r], __shfl_xor(pm[r], mk));

    float p[4][4], alpha[4], psum[4];
#pragma unroll
    for (int r = 0; r < 4; ++r) {
      const float mnew = fmaxf(mst[r], pm[r] * sc);
      alpha[r] = exp2f(mst[r] - mnew);
      mst[r] = mnew;
      float s_ = 0.f;
#pragma unroll
      for (int kt = 0; kt < 4; ++kt) {
        const float pe = exp2f(sacc[kt][r] * sc - mnew);
        p[kt][r] = pe;
        s_ += pe;
      }
      psum[r] = s_;
    }
#pragma unroll
    for (int mk = 1; mk < 16; mk <<= 1)
#pragma unroll
      for (int r = 0; r < 4; ++r) psum[r] += __shfl_xor(psum[r], mk);
#pragma unroll
    for (int r = 0; r < 4; ++r) lst[r] = lst[r] * alpha[r] + psum[r];
#pragma unroll
    for (int dt = 0; dt < 4; ++dt)
#pragma unroll
      for (int r = 0; r < 4; ++r) oacc[dt][r] *= alpha[r];

    // P -> per-wave LDS (swizzled), transposing score layout -> A-frag layout
    bf16_t* Pw = &Ps[w][0];
#pragma unroll
    for (int kt = 0; kt < 4; ++kt)
#pragma unroll
      for (int r = 0; r < 4; ++r) {
        const int row = lg * 4 + r;
        const int col = kt * 16 + lr;
        Pw[(row << 6) + (col ^ ((row & 7) << 3))] = (bf16_t)p[kt][r];
      }

    // O += P V  (A = P[q=l&15][k-chunk], B = Vt[d=dt*16+l&15][k-chunk])
#pragma unroll
    for (int c = 0; c < 2; ++c) {
      const int psw = lr & 7;
      bf16x8 pf = *reinterpret_cast<const bf16x8*>(Pw + (lr << 6) + (((c * 4 + lg) ^ psw) << 3));
#pragma unroll
      for (int dt = 0; dt < 4; ++dt) {
        const int vrow = dt * 16 + lr;
        bf16x8 vf = *reinterpret_cast<const bf16x8*>(Vs + (vrow << 6) + (((c * 4 + lg) ^ (vrow & 7)) << 3));
        oacc[dt] = mfma16(pf, vf, oacc[dt]);
      }
    }
    __syncthreads();
  }

  // epilogue: O[b*S+q][h*64+d] bf16
  const int b = bh >> 4, h = bh & 15;
#pragma unroll
  for (int r = 0; r < 4; ++r) {
    const float inv = 1.f / lst[r];
    const int qrow = q0 + lg * 4 + r;
    const size_t base = (((size_t)b * S_LEN + qrow) << 10) + (h << 6);
#pragma unroll
    for (int dt = 0; dt < 4; ++dt)
      Og[base + dt * 16 + lr] = (bf16_t)(oacc[dt][r] * inv);
  }
}

// ---------------------------------------------------------------------------
extern "C" void kernel_launch(void* const* d_in, const int* in_sizes, int n_in,
                              void* d_out, int out_size, void* d_ws, size_t ws_size,
                              hipStream_t stream) {
  const float* x = (const float*)d_in[0];
  const float* Wq = (const float*)d_in[1];
  const float* bq = (const float*)d_in[2];
  const float* Wk = (const float*)d_in[3];
  const float* bk = (const float*)d_in[4];
  const float* Wv = (const float*)d_in[5];
  const float* bv = (const float*)d_in[6];
  const float* Wo = (const float*)d_in[7];
  const float* bo = (const float*)d_in[8];
  const float* qnw = (const float*)d_in[9];
  const float* qnb = (const float*)d_in[10];
  const float* knw = (const float*)d_in[11];
  const float* knb = (const float*)d_in[12];
  float* out = (float*)d_out;

  uint8_t* ws = (uint8_t*)d_ws;
  // ws layout (bytes): total 48 MiB
  bf16_t* xb = (bf16_t*)(ws + 0);          // [4096][1024]      8388608
  bf16_t* Wb = (bf16_t*)(ws + 8388608);    // [3072][1024]      6291456
  bf16_t* Wob = (bf16_t*)(ws + 14680064);  // [1024][1024]      2097152
  bf16_t* Qb = (bf16_t*)(ws + 16777216);   // [32][2048][64]    8388608
  bf16_t* Kb = (bf16_t*)(ws + 25165824);   // [32][2048][64]    8388608
  bf16_t* Vt = (bf16_t*)(ws + 33554432);   // [32][64][2048]    8388608
  bf16_t* Ob = (bf16_t*)(ws + 41943040);   // [4096][1024]      8388608

  cvt_bf16<<<4096, 256, 0, stream>>>(x, xb, 4194304);
  cvt_bf16<<<1024, 256, 0, stream>>>(Wq, Wb, 1048576);
  cvt_bf16<<<1024, 256, 0, stream>>>(Wk, Wb + 1048576, 1048576);
  cvt_bf16<<<1024, 256, 0, stream>>>(Wv, Wb + 2097152, 1048576);
  cvt_bf16<<<1024, 256, 0, stream>>>(Wo, Wob, 1048576);

  gemm_qkv_ln<<<dim3(24, 32), 256, 0, stream>>>(xb, Wb, bq, bk, bv, qnw, qnb, knw, knb,
                                                Qb, Kb, Vt);
  attn_kernel<<<dim3(32, 32), 256, 0, stream>>>(Qb, Kb, Vt, Ob);
  gemm_out<<<dim3(8, 32), 256, 0, stream>>>(Ob, Wob, bo, out);
}

// Round 2
// 138.476 us; speedup vs baseline: 1.4909x; 1.4909x over previous
//
#include <hip/hip_runtime.h>
#include <stdint.h>

// ---------------------------------------------------------------------------
// Fused MHA forward: B=2, S=2048, E=1024, H=16, D=64, fp32 in/out,
// bf16 MFMA compute internally.
// ---------------------------------------------------------------------------

typedef __bf16 bf16_t;
typedef __bf16 bf16x8 __attribute__((ext_vector_type(8)));
typedef __bf16 bf16x4 __attribute__((ext_vector_type(4)));
typedef __bf16 bf16x2 __attribute__((ext_vector_type(2)));
typedef float f32x4 __attribute__((ext_vector_type(4)));
typedef float f32x16 __attribute__((ext_vector_type(16)));
typedef uint32_t u32x4 __attribute__((ext_vector_type(4)));

#define S_LEN 2048

__device__ __forceinline__ void load_lds16(const void* g, void* l) {
  __builtin_amdgcn_global_load_lds((__attribute__((address_space(1))) void*)g,
                                   (__attribute__((address_space(3))) void*)l,
                                   16, 0, 0);
}

__device__ __forceinline__ f32x4 mfma16(bf16x8 a, bf16x8 b, f32x4 c) {
  return __builtin_amdgcn_mfma_f32_16x16x32_bf16(a, b, c, 0, 0, 0);
}

__device__ __forceinline__ f32x16 mfma32(bf16x8 a, bf16x8 b, f32x16 c) {
  return __builtin_amdgcn_mfma_f32_32x32x16_bf16(a, b, c, 0, 0, 0);
}

__device__ __forceinline__ uint32_t pk_bf16(float a, float b) {
  bf16x2 v; v[0] = (bf16_t)a; v[1] = (bf16_t)b;
  return __builtin_bit_cast(uint32_t, v);
}

__device__ __forceinline__ void plswap(uint32_t& a, uint32_t& b) {
  // a' = [a.lo32lanes, b.lo32lanes], b' = [a.hi32lanes, b.hi32lanes]
  asm volatile("v_permlane32_swap_b32 %0, %1" : "+v"(a), "+v"(b));
}

// ---------------- fp32 -> bf16 convert (vectorized) ----------------
__global__ void cvt_bf16(const float* __restrict__ in, bf16_t* __restrict__ out, int n) {
  int i = (blockIdx.x * blockDim.x + threadIdx.x) * 4;
  if (i >= n) return;
  float4 v = *reinterpret_cast<const float4*>(in + i);
  bf16x4 o;
  o[0] = (bf16_t)v.x; o[1] = (bf16_t)v.y; o[2] = (bf16_t)v.z; o[3] = (bf16_t)v.w;
  *reinterpret_cast<bf16x4*>(out + i) = o;
}

// ---------------- common 128x128 / BK=32 GEMM core (K=1024) ----------------
__device__ __forceinline__ void gemm_main(const bf16_t* __restrict__ ga,
                                          const bf16_t* __restrict__ gb,
                                          bf16_t* As, bf16_t* Bs,
                                          int t, int wr, int wc, int lg, int lr,
                                          f32x4 (&acc)[4][4]) {
  for (int k0 = 0; k0 < 1024; k0 += 32) {
    load_lds16(ga + k0,          As + t * 8);
    load_lds16(ga + 65536 + k0,  As + 2048 + t * 8);   // +64 rows
    load_lds16(gb + k0,          Bs + t * 8);
    load_lds16(gb + 65536 + k0,  Bs + 2048 + t * 8);
    __syncthreads();
    bf16x8 af[4], bfr[4];
#pragma unroll
    for (int mt = 0; mt < 4; ++mt)
      af[mt] = *reinterpret_cast<const bf16x8*>(As + ((wr * 64 + mt * 16 + lr) << 5) + lg * 8);
#pragma unroll
    for (int nt = 0; nt < 4; ++nt)
      bfr[nt] = *reinterpret_cast<const bf16x8*>(Bs + ((wc * 64 + nt * 16 + lr) << 5) + lg * 8);
#pragma unroll
    for (int mt = 0; mt < 4; ++mt)
#pragma unroll
      for (int nt = 0; nt < 4; ++nt)
        acc[mt][nt] = mfma16(af[mt], bfr[nt], acc[mt][nt]);
    __syncthreads();
  }
}

// ---------------- GEMM1: QKV projection + bias + per-head LN ----------------
__launch_bounds__(256, 2)
__global__ void gemm_qkv_ln(const bf16_t* __restrict__ A, const bf16_t* __restrict__ Bt,
                            const float* __restrict__ bq, const float* __restrict__ bk,
                            const float* __restrict__ bv,
                            const float* __restrict__ qnw, const float* __restrict__ qnb,
                            const float* __restrict__ knw, const float* __restrict__ knb,
                            bf16_t* __restrict__ Qb, bf16_t* __restrict__ Kb,
                            bf16_t* __restrict__ Vt) {
  __shared__ alignas(16) bf16_t As[128 * 32];
  __shared__ alignas(16) bf16_t Bs[128 * 32];
  const int t = threadIdx.x;
  const int bm = blockIdx.y, bn = blockIdx.x;
  const int w = t >> 6, lane = t & 63;
  const int wr = w >> 1, wc = w & 1;
  const int lg = lane >> 4, lr = lane & 15;

  f32x4 acc[4][4] = {};
  const int srow = t >> 2;
  const int scol = (t & 3) << 3;
  const bf16_t* ga = A + ((size_t)(bm * 128 + srow) << 10) + scol;
  const bf16_t* gb = Bt + ((size_t)(bn * 128 + srow) << 10) + scol;
  gemm_main(ga, gb, As, Bs, t, wr, wc, lg, lr, acc);

  const int nbase = bn * 128 + wc * 64;
  const int region = nbase >> 10;         // 0=Q 1=K 2=V
  const int h = (nbase & 1023) >> 6;

  if (region == 2) {
#pragma unroll
    for (int mt = 0; mt < 4; ++mt)
#pragma unroll
      for (int r = 0; r < 4; ++r) {
        const int gm = bm * 128 + wr * 64 + mt * 16 + lg * 4 + r;
        const int b = gm >> 11, s = gm & 2047;
#pragma unroll
        for (int nt = 0; nt < 4; ++nt) {
          const int d = nt * 16 + lr;
          float val = acc[mt][nt][r] + bv[h * 64 + d];
          Vt[((size_t)((b * 16 + h) * 64 + d) << 11) + s] = (bf16_t)val;
        }
      }
  } else {
    const float* bias = region ? bk : bq;
    const float* lw = region ? knw : qnw;
    const float* lb = region ? knb : qnb;
    bf16_t* Outp = region ? Kb : Qb;
#pragma unroll
    for (int mt = 0; mt < 4; ++mt)
#pragma unroll
      for (int r = 0; r < 4; ++r) {
        const int gm = bm * 128 + wr * 64 + mt * 16 + lg * 4 + r;
        const int b = gm >> 11, s = gm & 2047;
        float vv[4], sum = 0.f, sumsq = 0.f;
#pragma unroll
        for (int nt = 0; nt < 4; ++nt) {
          const int d = nt * 16 + lr;
          vv[nt] = acc[mt][nt][r] + bias[h * 64 + d];
          sum += vv[nt];
          sumsq += vv[nt] * vv[nt];
        }
#pragma unroll
        for (int mk = 1; mk < 16; mk <<= 1) {
          sum += __shfl_xor(sum, mk);
          sumsq += __shfl_xor(sumsq, mk);
        }
        const float mean = sum * (1.f / 64.f);
        const float var = sumsq * (1.f / 64.f) - mean * mean;
        const float rstd = rsqrtf(var + 1e-5f);
        const size_t rowoff = ((size_t)((b * 16 + h) * 2048 + s)) << 6;
#pragma unroll
        for (int nt = 0; nt < 4; ++nt) {
          const int d = nt * 16 + lr;
          float y = (vv[nt] - mean) * rstd * lw[d] + lb[d];
          Outp[rowoff + d] = (bf16_t)y;
        }
      }
  }
}

// ---------------- GEMM2: output projection -> fp32 d_out ----------------
__launch_bounds__(256, 2)
__global__ void gemm_out(const bf16_t* __restrict__ A, const bf16_t* __restrict__ Bt,
                         const float* __restrict__ bo, float* __restrict__ dout) {
  __shared__ alignas(16) bf16_t As[128 * 32];
  __shared__ alignas(16) bf16_t Bs[128 * 32];
  const int t = threadIdx.x;
  const int bm = blockIdx.y, bn = blockIdx.x;
  const int w = t >> 6, lane = t & 63;
  const int wr = w >> 1, wc = w & 1;
  const int lg = lane >> 4, lr = lane & 15;

  f32x4 acc[4][4] = {};
  const int srow = t >> 2;
  const int scol = (t & 3) << 3;
  const bf16_t* ga = A + ((size_t)(bm * 128 + srow) << 10) + scol;
  const bf16_t* gb = Bt + ((size_t)(bn * 128 + srow) << 10) + scol;
  gemm_main(ga, gb, As, Bs, t, wr, wc, lg, lr, acc);

#pragma unroll
  for (int mt = 0; mt < 4; ++mt)
#pragma unroll
    for (int r = 0; r < 4; ++r) {
      const int gm = bm * 128 + wr * 64 + mt * 16 + lg * 4 + r;
#pragma unroll
      for (int nt = 0; nt < 4; ++nt) {
        const int gn = bn * 128 + wc * 64 + nt * 16 + lr;
        dout[((size_t)gm << 10) + gn] = acc[mt][nt][r] + bo[gn];
      }
    }
}

// ---------------- flash attention, 32x32 swapped-operand structure ----------
// Block: 4 waves, each wave owns 32 q-rows (block = 128 q). Grid (16, 32).
// KV tile = 64 keys, double-buffered LDS, XOR-swizzled via pre-swizzled
// global_load_lds source. Swapped QK^T (A=K,B=Q) -> q = lane&31 lane-local;
// swapped PV (A=V^T, B=P^T) keeps O q-lane-local. P assembled in-register
// via cvt_pk + v_permlane32_swap_b32 (T12). Defer-max (T13, THR=8).
__launch_bounds__(256, 2)
__global__ void attn_kernel(const bf16_t* __restrict__ Qb, const bf16_t* __restrict__ Kb,
                            const bf16_t* __restrict__ Vt, bf16_t* __restrict__ Og) {
  __shared__ alignas(16) bf16_t Ks[2][64 * 64];
  __shared__ alignas(16) bf16_t Vs[2][64 * 64];

  const int t = threadIdx.x;
  const int w = t >> 6, lane = t & 63;
  const int lq = lane & 31;   // q index (and A-row index)
  const int hi = lane >> 5;
  const int bh = blockIdx.y;
  const int b = bh >> 4, h = bh & 15;
  const int q0 = blockIdx.x * 128 + w * 32;

  // Q fragments: lane holds Q[q0+lq][c*16 + hi*8 .. +8] for c=0..3
  bf16x8 qf[4];
  {
    const bf16_t* qp = Qb + (((size_t)bh * S_LEN + q0 + lq) << 6) + hi * 8;
#pragma unroll
    for (int c = 0; c < 4; ++c)
      qf[c] = *reinterpret_cast<const bf16x8*>(qp + c * 16);
  }

  f32x16 oacc0 = {}, oacc1 = {};   // O[d][q]: q=lane&31, d over regs (2 halves)
  float m_ = -1e30f, l_ = 0.f;
  const float sc = 0.125f * 1.44269504f;  // 1/sqrt(D) * log2(e)

  const int sr = t >> 3;                      // staging row 0..31
  const int ssw = ((t & 7) ^ (sr & 7)) << 3;  // swizzled source col (elems)
  const bf16_t* kbase = Kb + (((size_t)bh * S_LEN) << 6);
  const bf16_t* vbase = Vt + ((size_t)bh << 17);

#define STAGE(buf, j)                                                        \
  {                                                                          \
    const bf16_t* kb = kbase + ((size_t)((j) * 64) << 6);                    \
    const bf16_t* vb = vbase + (j) * 64;                                     \
    load_lds16(kb + (sr << 6) + ssw,        &Ks[buf][t * 8]);                \
    load_lds16(kb + ((sr + 32) << 6) + ssw, &Ks[buf][2048 + t * 8]);         \
    load_lds16(vb + sr * S_LEN + ssw,        &Vs[buf][t * 8]);               \
    load_lds16(vb + (sr + 32) * S_LEN + ssw, &Vs[buf][2048 + t * 8]);        \
  }

  STAGE(0, 0);
  __syncthreads();

  for (int j = 0; j < 32; ++j) {
    const int cur = j & 1;
    if (j < 31) STAGE(cur ^ 1, j + 1);

    // ---- QK^T: S[key][q], key-halves kh=0,1; accumulate over d (4 chunks)
    f32x16 sa0, sa1;
    {
      f32x16 z0 = {}, z1 = {};
      const int row0 = lq, row1 = 32 + lq;
      const bf16_t* kr0 = &Ks[cur][row0 << 6];
      const bf16_t* kr1 = &Ks[cur][row1 << 6];
      const int sw0 = row0 & 7, sw1 = row1 & 7;
#pragma unroll
      for (int c = 0; c < 4; ++c) {
        bf16x8 kf0 = *reinterpret_cast<const bf16x8*>(kr0 + (((c * 2 + hi) ^ sw0) << 3));
        z0 = mfma32(kf0, qf[c], z0);
      }
#pragma unroll
      for (int c = 0; c < 4; ++c) {
        bf16x8 kf1 = *reinterpret_cast<const bf16x8*>(kr1 + (((c * 2 + hi) ^ sw1) << 3));
        z1 = mfma32(kf1, qf[c], z1);
      }
      sa0 = z0; sa1 = z1;
    }

    // ---- online softmax (log2 domain), q lane-local
    float mv[16];
#pragma unroll
    for (int i = 0; i < 16; ++i) mv[i] = fmaxf(sa0[i], sa1[i]);
#pragma unroll
    for (int s2 = 8; s2 >= 1; s2 >>= 1)
#pragma unroll
      for (int i = 0; i < s2; ++i) mv[i] = fmaxf(mv[i], mv[i + s2]);
    float mx = fmaxf(mv[0], __shfl_xor(mv[0], 32));
    const float ms = mx * sc;

    if (__any(ms > m_ + 8.f)) {   // defer-max: rescale only on real growth
      const float mn = fmaxf(m_, ms);
      const float alpha = __builtin_amdgcn_exp2f(m_ - mn);
      oacc0 *= alpha; oacc1 *= alpha;
      l_ *= alpha;
      m_ = mn;
    }

    const float mneg = -m_;
    f32x16 p0, p1;
#pragma unroll
    for (int i = 0; i < 16; ++i) p0[i] = __builtin_amdgcn_exp2f(__builtin_fmaf(sa0[i], sc, mneg));
#pragma unroll
    for (int i = 0; i < 16; ++i) p1[i] = __builtin_amdgcn_exp2f(__builtin_fmaf(sa1[i], sc, mneg));

    float sv[16];
#pragma unroll
    for (int i = 0; i < 16; ++i) sv[i] = p0[i] + p1[i];
#pragma unroll
    for (int s2 = 8; s2 >= 1; s2 >>= 1)
#pragma unroll
      for (int i = 0; i < s2; ++i) sv[i] += sv[i + s2];
    l_ += sv[0] + __shfl_xor(sv[0], 32);

    // ---- PV: O[d][q] += V^T · P^T, 4 key-chunks of 16
#pragma unroll
    for (int c = 0; c < 4; ++c) {
      const f32x16 ph = (c < 2) ? p0 : p1;
      const int cl = c & 1;
      uint32_t w00 = pk_bf16(ph[8 * cl + 0], ph[8 * cl + 1]);
      uint32_t w01 = pk_bf16(ph[8 * cl + 2], ph[8 * cl + 3]);
      uint32_t w10 = pk_bf16(ph[8 * cl + 4], ph[8 * cl + 5]);
      uint32_t w11 = pk_bf16(ph[8 * cl + 6], ph[8 * cl + 7]);
      plswap(w00, w10);
      plswap(w01, w11);
      u32x4 pw = {w00, w01, w10, w11};
      bf16x8 pf = __builtin_bit_cast(bf16x8, pw);
      {
        const int vrow = lq;
        bf16x8 vf = *reinterpret_cast<const bf16x8*>(
            &Vs[cur][(vrow << 6) + (((c * 2 + hi) ^ (vrow & 7)) << 3)]);
        oacc0 = mfma32(vf, pf, oacc0);
      }
      {
        const int vrow = 32 + lq;
        bf16x8 vf = *reinterpret_cast<const bf16x8*>(
            &Vs[cur][(vrow << 6) + (((c * 2 + hi) ^ (vrow & 7)) << 3)]);
        oacc1 = mfma32(vf, pf, oacc1);
      }
    }
    __syncthreads();
  }

  // ---- epilogue: normalize, transpose via LDS (reuse Ks), coalesced store
  __syncthreads();   // all warps done reading Ks/Vs
  bf16_t* Os = &Ks[0][0] + w * 2048;   // 4KB per warp: [32 q][64 d] swizzled
  const float inv = __builtin_amdgcn_rcpf(l_);
#pragma unroll
  for (int dh = 0; dh < 2; ++dh) {
    const f32x16 oa = dh ? oacc1 : oacc0;
#pragma unroll
    for (int g = 0; g < 8; ++g) {
      const int reg = g * 2;
      const int dl = (reg & 3) + 8 * (reg >> 2) + 4 * hi;
      const int d = dh * 32 + dl;           // d, d+1 from regs (reg, reg+1)
      const uint32_t wv = pk_bf16(oa[reg] * inv, oa[reg + 1] * inv);
      const int byte = lq * 128 + ((((d >> 3) ^ (lq & 7))) << 4) + ((d & 7) << 1);
      *reinterpret_cast<uint32_t*>(reinterpret_cast<char*>(Os) + byte) = wv;
    }
  }
#pragma unroll
  for (int it = 0; it < 4; ++it) {
    const int q = it * 8 + (lane >> 3);
    const int ch = lane & 7;
    bf16x8 ov = *reinterpret_cast<const bf16x8*>(
        reinterpret_cast<char*>(Os) + q * 128 + ((ch ^ (q & 7)) << 4));
    const size_t gaddr = (((size_t)(b * S_LEN + q0 + q)) << 10) + h * 64 + ch * 8;
    *reinterpret_cast<bf16x8*>(Og + gaddr) = ov;
  }
#undef STAGE
}

// ---------------------------------------------------------------------------
extern "C" void kernel_launch(void* const* d_in, const int* in_sizes, int n_in,
                              void* d_out, int out_size, void* d_ws, size_t ws_size,
                              hipStream_t stream) {
  const float* x = (const float*)d_in[0];
  const float* Wq = (const float*)d_in[1];
  const float* bq = (const float*)d_in[2];
  const float* Wk = (const float*)d_in[3];
  const float* bk = (const float*)d_in[4];
  const float* Wv = (const float*)d_in[5];
  const float* bv = (const float*)d_in[6];
  const float* Wo = (const float*)d_in[7];
  const float* bo = (const float*)d_in[8];
  const float* qnw = (const float*)d_in[9];
  const float* qnb = (const float*)d_in[10];
  const float* knw = (const float*)d_in[11];
  const float* knb = (const float*)d_in[12];
  float* out = (float*)d_out;

  uint8_t* ws = (uint8_t*)d_ws;
  bf16_t* xb = (bf16_t*)(ws + 0);          // [4096][1024]      8388608
  bf16_t* Wb = (bf16_t*)(ws + 8388608);    // [3072][1024]      6291456
  bf16_t* Wob = (bf16_t*)(ws + 14680064);  // [1024][1024]      2097152
  bf16_t* Qb = (bf16_t*)(ws + 16777216);   // [32][2048][64]    8388608
  bf16_t* Kb = (bf16_t*)(ws + 25165824);   // [32][2048][64]    8388608
  bf16_t* Vt = (bf16_t*)(ws + 33554432);   // [32][64][2048]    8388608
  bf16_t* Ob = (bf16_t*)(ws + 41943040);   // [4096][1024]      8388608

  cvt_bf16<<<4096, 256, 0, stream>>>(x, xb, 4194304);
  cvt_bf16<<<1024, 256, 0, stream>>>(Wq, Wb, 1048576);
  cvt_bf16<<<1024, 256, 0, stream>>>(Wk, Wb + 1048576, 1048576);
  cvt_bf16<<<1024, 256, 0, stream>>>(Wv, Wb + 2097152, 1048576);
  cvt_bf16<<<1024, 256, 0, stream>>>(Wo, Wob, 1048576);

  gemm_qkv_ln<<<dim3(24, 32), 256, 0, stream>>>(xb, Wb, bq, bk, bv, qnw, qnb, knw, knb,
                                                Qb, Kb, Vt);
  attn_kernel<<<dim3(16, 32), 256, 0, stream>>>(Qb, Kb, Vt, Ob);
  gemm_out<<<dim3(8, 32), 256, 0, stream>>>(Ob, Wob, bo, out);
}

// Round 3
// 131.622 us; speedup vs baseline: 1.5685x; 1.0521x over previous
//
#include <hip/hip_runtime.h>
#include <stdint.h>

// ---------------------------------------------------------------------------
// Fused MHA forward: B=2, S=2048, E=1024, H=16, D=64, fp32 in/out,
// bf16 MFMA compute internally.
// ---------------------------------------------------------------------------

typedef __bf16 bf16_t;
typedef __bf16 bf16x8 __attribute__((ext_vector_type(8)));
typedef __bf16 bf16x4 __attribute__((ext_vector_type(4)));
typedef __bf16 bf16x2 __attribute__((ext_vector_type(2)));
typedef float f32x4 __attribute__((ext_vector_type(4)));
typedef float f32x16 __attribute__((ext_vector_type(16)));
typedef uint32_t u32x4 __attribute__((ext_vector_type(4)));

#define S_LEN 2048

__device__ __forceinline__ void load_lds16(const void* g, void* l) {
  __builtin_amdgcn_global_load_lds((__attribute__((address_space(1))) void*)g,
                                   (__attribute__((address_space(3))) void*)l,
                                   16, 0, 0);
}

__device__ __forceinline__ f32x4 mfma16(bf16x8 a, bf16x8 b, f32x4 c) {
  return __builtin_amdgcn_mfma_f32_16x16x32_bf16(a, b, c, 0, 0, 0);
}

__device__ __forceinline__ f32x16 mfma32(bf16x8 a, bf16x8 b, f32x16 c) {
  return __builtin_amdgcn_mfma_f32_32x32x16_bf16(a, b, c, 0, 0, 0);
}

__device__ __forceinline__ uint32_t pk_bf16(float a, float b) {
  bf16x2 v; v[0] = (bf16_t)a; v[1] = (bf16_t)b;
  return __builtin_bit_cast(uint32_t, v);
}

__device__ __forceinline__ void plswap(uint32_t& a, uint32_t& b) {
  asm volatile("v_permlane32_swap_b32 %0, %1" : "+v"(a), "+v"(b));
}

// ---------------- fp32 -> bf16 convert, all tensors in one launch ----------
__global__ void cvt_all(const float* __restrict__ x, const float* __restrict__ Wq,
                        const float* __restrict__ Wk, const float* __restrict__ Wv,
                        const float* __restrict__ Wo,
                        bf16_t* __restrict__ xb, bf16_t* __restrict__ Wb,
                        bf16_t* __restrict__ Wob) {
  const int bid = blockIdx.x;
  const float* src; bf16_t* dst; int idx;
  if (bid < 4096) { src = x; dst = xb; idx = bid; }
  else {
    const int r = bid - 4096, rg = r >> 10;
    idx = r & 1023;
    if (rg == 0)      { src = Wq; dst = Wb; }
    else if (rg == 1) { src = Wk; dst = Wb + (1 << 20); }
    else if (rg == 2) { src = Wv; dst = Wb + (2 << 20); }
    else              { src = Wo; dst = Wob; }
  }
  const int i = (idx * 256 + threadIdx.x) * 4;
  float4 v = *reinterpret_cast<const float4*>(src + i);
  bf16x4 o;
  o[0] = (bf16_t)v.x; o[1] = (bf16_t)v.y; o[2] = (bf16_t)v.z; o[3] = (bf16_t)v.w;
  *reinterpret_cast<bf16x4*>(dst + i) = o;
}

// ---------------- common 128x128 / BK=32 GEMM core (K=1024) ----------------
__device__ __forceinline__ void gemm_main(const bf16_t* __restrict__ ga,
                                          const bf16_t* __restrict__ gb,
                                          bf16_t* As, bf16_t* Bs,
                                          int t, int wr, int wc, int lg, int lr,
                                          f32x4 (&acc)[4][4]) {
  for (int k0 = 0; k0 < 1024; k0 += 32) {
    load_lds16(ga + k0,          As + t * 8);
    load_lds16(ga + 65536 + k0,  As + 2048 + t * 8);
    load_lds16(gb + k0,          Bs + t * 8);
    load_lds16(gb + 65536 + k0,  Bs + 2048 + t * 8);
    __syncthreads();
    bf16x8 af[4], bfr[4];
#pragma unroll
    for (int mt = 0; mt < 4; ++mt)
      af[mt] = *reinterpret_cast<const bf16x8*>(As + ((wr * 64 + mt * 16 + lr) << 5) + lg * 8);
#pragma unroll
    for (int nt = 0; nt < 4; ++nt)
      bfr[nt] = *reinterpret_cast<const bf16x8*>(Bs + ((wc * 64 + nt * 16 + lr) << 5) + lg * 8);
#pragma unroll
    for (int mt = 0; mt < 4; ++mt)
#pragma unroll
      for (int nt = 0; nt < 4; ++nt)
        acc[mt][nt] = mfma16(af[mt], bfr[nt], acc[mt][nt]);
    __syncthreads();
  }
}

// ---------------- GEMM1: QKV projection + bias + per-head LN ----------------
__launch_bounds__(256, 2)
__global__ void gemm_qkv_ln(const bf16_t* __restrict__ A, const bf16_t* __restrict__ Bt,
                            const float* __restrict__ bq, const float* __restrict__ bk,
                            const float* __restrict__ bv,
                            const float* __restrict__ qnw, const float* __restrict__ qnb,
                            const float* __restrict__ knw, const float* __restrict__ knb,
                            bf16_t* __restrict__ Qb, bf16_t* __restrict__ Kb,
                            bf16_t* __restrict__ Vt) {
  __shared__ alignas(16) bf16_t As[128 * 32];
  __shared__ alignas(16) bf16_t Bs[128 * 32];
  const int t = threadIdx.x;
  const int bm = blockIdx.y, bn = blockIdx.x;
  const int w = t >> 6, lane = t & 63;
  const int wr = w >> 1, wc = w & 1;
  const int lg = lane >> 4, lr = lane & 15;

  f32x4 acc[4][4] = {};
  const int srow = t >> 2;
  const int scol = (t & 3) << 3;
  const bf16_t* ga = A + ((size_t)(bm * 128 + srow) << 10) + scol;
  const bf16_t* gb = Bt + ((size_t)(bn * 128 + srow) << 10) + scol;
  gemm_main(ga, gb, As, Bs, t, wr, wc, lg, lr, acc);

  const int nbase = bn * 128 + wc * 64;
  const int region = nbase >> 10;         // 0=Q 1=K 2=V
  const int h = (nbase & 1023) >> 6;

  if (region == 2) {
#pragma unroll
    for (int mt = 0; mt < 4; ++mt)
#pragma unroll
      for (int r = 0; r < 4; ++r) {
        const int gm = bm * 128 + wr * 64 + mt * 16 + lg * 4 + r;
        const int b = gm >> 11, s = gm & 2047;
#pragma unroll
        for (int nt = 0; nt < 4; ++nt) {
          const int d = nt * 16 + lr;
          float val = acc[mt][nt][r] + bv[h * 64 + d];
          Vt[((size_t)((b * 16 + h) * 64 + d) << 11) + s] = (bf16_t)val;
        }
      }
  } else {
    const float* bias = region ? bk : bq;
    const float* lw = region ? knw : qnw;
    const float* lb = region ? knb : qnb;
    bf16_t* Outp = region ? Kb : Qb;
#pragma unroll
    for (int mt = 0; mt < 4; ++mt)
#pragma unroll
      for (int r = 0; r < 4; ++r) {
        const int gm = bm * 128 + wr * 64 + mt * 16 + lg * 4 + r;
        const int b = gm >> 11, s = gm & 2047;
        float vv[4], sum = 0.f, sumsq = 0.f;
#pragma unroll
        for (int nt = 0; nt < 4; ++nt) {
          const int d = nt * 16 + lr;
          vv[nt] = acc[mt][nt][r] + bias[h * 64 + d];
          sum += vv[nt];
          sumsq += vv[nt] * vv[nt];
        }
#pragma unroll
        for (int mk = 1; mk < 16; mk <<= 1) {
          sum += __shfl_xor(sum, mk);
          sumsq += __shfl_xor(sumsq, mk);
        }
        const float mean = sum * (1.f / 64.f);
        const float var = sumsq * (1.f / 64.f) - mean * mean;
        const float rstd = rsqrtf(var + 1e-5f);
        const size_t rowoff = ((size_t)((b * 16 + h) * 2048 + s)) << 6;
#pragma unroll
        for (int nt = 0; nt < 4; ++nt) {
          const int d = nt * 16 + lr;
          float y = (vv[nt] - mean) * rstd * lw[d] + lb[d];
          Outp[rowoff + d] = (bf16_t)y;
        }
      }
  }
}

// ---------------- GEMM2: output projection, 64x128 tile -> 512 blocks -------
__launch_bounds__(256, 2)
__global__ void gemm_out(const bf16_t* __restrict__ A, const bf16_t* __restrict__ Bt,
                         const float* __restrict__ bo, float* __restrict__ dout) {
  __shared__ alignas(16) bf16_t As[64 * 32];
  __shared__ alignas(16) bf16_t Bs[128 * 32];
  const int t = threadIdx.x;
  const int bm = blockIdx.y, bn = blockIdx.x;
  const int w = t >> 6, lane = t & 63;
  const int wr = w >> 1, wc = w & 1;           // wave tile 32x64
  const int lg = lane >> 4, lr = lane & 15;

  f32x4 acc[2][4] = {};
  const int srow = t >> 2;                      // 0..63
  const int scol = (t & 3) << 3;
  const bf16_t* ga = A + ((size_t)(bm * 64 + srow) << 10) + scol;
  const bf16_t* gb = Bt + ((size_t)(bn * 128 + srow) << 10) + scol;

  for (int k0 = 0; k0 < 1024; k0 += 32) {
    load_lds16(ga + k0,          As + t * 8);
    load_lds16(gb + k0,          Bs + t * 8);
    load_lds16(gb + 65536 + k0,  Bs + 2048 + t * 8);
    __syncthreads();
    bf16x8 af[2], bfr[4];
#pragma unroll
    for (int mt = 0; mt < 2; ++mt)
      af[mt] = *reinterpret_cast<const bf16x8*>(As + ((wr * 32 + mt * 16 + lr) << 5) + lg * 8);
#pragma unroll
    for (int nt = 0; nt < 4; ++nt)
      bfr[nt] = *reinterpret_cast<const bf16x8*>(Bs + ((wc * 64 + nt * 16 + lr) << 5) + lg * 8);
#pragma unroll
    for (int mt = 0; mt < 2; ++mt)
#pragma unroll
      for (int nt = 0; nt < 4; ++nt)
        acc[mt][nt] = mfma16(af[mt], bfr[nt], acc[mt][nt]);
    __syncthreads();
  }

#pragma unroll
  for (int mt = 0; mt < 2; ++mt)
#pragma unroll
    for (int r = 0; r < 4; ++r) {
      const int gm = bm * 64 + wr * 32 + mt * 16 + lg * 4 + r;
#pragma unroll
      for (int nt = 0; nt < 4; ++nt) {
        const int gn = bn * 128 + wc * 64 + nt * 16 + lr;
        dout[((size_t)gm << 10) + gn] = acc[mt][nt][r] + bo[gn];
      }
    }
}

// ---------------- flash attention, 32x32 swapped-operand, KV-split ----------
// Block: 4 waves x 32 q = 128 q. Grid (16, 32, NSPLIT). Each z-half covers
// 32/NSPLIT KV tiles of 64 keys. NSPLIT=2: writes fp32 unnormalized O + (m,l)
// partials (combined by attn_combine); NSPLIT=1: direct bf16 output.
template <int NSPLIT>
__launch_bounds__(256, 4)
__global__ void attn_kernel(const bf16_t* __restrict__ Qb, const bf16_t* __restrict__ Kb,
                            const bf16_t* __restrict__ Vt, bf16_t* __restrict__ Og,
                            float* __restrict__ Op, float* __restrict__ Ml) {
  __shared__ alignas(16) bf16_t KVs[4][64 * 64];  // [0..1]=K dbuf, [2..3]=V dbuf

  const int t = threadIdx.x;
  const int w = t >> 6, lane = t & 63;
  const int lq = lane & 31;
  const int hi = lane >> 5;
  const int bh = blockIdx.y;
  const int z = (NSPLIT == 1) ? 0 : blockIdx.z;
  const int b = bh >> 4, h = bh & 15;
  const int q0 = blockIdx.x * 128 + w * 32;
  const int ntiles = 32 / NSPLIT;

  bf16x8 qf[4];
  {
    const bf16_t* qp = Qb + (((size_t)bh * S_LEN + q0 + lq) << 6) + hi * 8;
#pragma unroll
    for (int c = 0; c < 4; ++c)
      qf[c] = *reinterpret_cast<const bf16x8*>(qp + c * 16);
  }

  f32x16 oacc0 = {}, oacc1 = {};
  float m_ = -1e30f, l_ = 0.f;
  const float sc = 0.125f * 1.44269504f;

  const int sr = t >> 3;
  const int ssw = ((t & 7) ^ (sr & 7)) << 3;
  const bf16_t* kbase = Kb + (((size_t)bh * S_LEN) << 6);
  const bf16_t* vbase = Vt + ((size_t)bh << 17);

#define STAGE(buf, jt)                                                       \
  {                                                                          \
    const bf16_t* kb = kbase + ((size_t)((jt) * 64) << 6);                   \
    const bf16_t* vb = vbase + (jt) * 64;                                    \
    load_lds16(kb + (sr << 6) + ssw,        &KVs[buf][t * 8]);               \
    load_lds16(kb + ((sr + 32) << 6) + ssw, &KVs[buf][2048 + t * 8]);        \
    load_lds16(vb + sr * S_LEN + ssw,        &KVs[2 + (buf)][t * 8]);        \
    load_lds16(vb + (sr + 32) * S_LEN + ssw, &KVs[2 + (buf)][2048 + t * 8]); \
  }

  STAGE(0, z * ntiles);
  __syncthreads();

  for (int j = 0; j < ntiles; ++j) {
    const int cur = j & 1;
    if (j < ntiles - 1) STAGE(cur ^ 1, z * ntiles + j + 1);

    f32x16 sa0, sa1;
    {
      f32x16 z0 = {}, z1 = {};
      const int row0 = lq, row1 = 32 + lq;
      const bf16_t* kr0 = &KVs[cur][row0 << 6];
      const bf16_t* kr1 = &KVs[cur][row1 << 6];
      const int sw0 = row0 & 7, sw1 = row1 & 7;
#pragma unroll
      for (int c = 0; c < 4; ++c) {
        bf16x8 kf0 = *reinterpret_cast<const bf16x8*>(kr0 + (((c * 2 + hi) ^ sw0) << 3));
        z0 = mfma32(kf0, qf[c], z0);
      }
#pragma unroll
      for (int c = 0; c < 4; ++c) {
        bf16x8 kf1 = *reinterpret_cast<const bf16x8*>(kr1 + (((c * 2 + hi) ^ sw1) << 3));
        z1 = mfma32(kf1, qf[c], z1);
      }
      sa0 = z0; sa1 = z1;
    }

    float mv[16];
#pragma unroll
    for (int i = 0; i < 16; ++i) mv[i] = fmaxf(sa0[i], sa1[i]);
#pragma unroll
    for (int s2 = 8; s2 >= 1; s2 >>= 1)
#pragma unroll
      for (int i = 0; i < s2; ++i) mv[i] = fmaxf(mv[i], mv[i + s2]);
    float mx = fmaxf(mv[0], __shfl_xor(mv[0], 32));
    const float ms = mx * sc;

    if (__any(ms > m_ + 8.f)) {
      const float mn = fmaxf(m_, ms);
      const float alpha = __builtin_amdgcn_exp2f(m_ - mn);
      oacc0 *= alpha; oacc1 *= alpha;
      l_ *= alpha;
      m_ = mn;
    }

    const float mneg = -m_;
    f32x16 p0, p1;
#pragma unroll
    for (int i = 0; i < 16; ++i) p0[i] = __builtin_amdgcn_exp2f(__builtin_fmaf(sa0[i], sc, mneg));
#pragma unroll
    for (int i = 0; i < 16; ++i) p1[i] = __builtin_amdgcn_exp2f(__builtin_fmaf(sa1[i], sc, mneg));

    float sv[16];
#pragma unroll
    for (int i = 0; i < 16; ++i) sv[i] = p0[i] + p1[i];
#pragma unroll
    for (int s2 = 8; s2 >= 1; s2 >>= 1)
#pragma unroll
      for (int i = 0; i < s2; ++i) sv[i] += sv[i + s2];
    l_ += sv[0] + __shfl_xor(sv[0], 32);

#pragma unroll
    for (int c = 0; c < 4; ++c) {
      const f32x16 ph = (c < 2) ? p0 : p1;
      const int cl = c & 1;
      uint32_t w00 = pk_bf16(ph[8 * cl + 0], ph[8 * cl + 1]);
      uint32_t w01 = pk_bf16(ph[8 * cl + 2], ph[8 * cl + 3]);
      uint32_t w10 = pk_bf16(ph[8 * cl + 4], ph[8 * cl + 5]);
      uint32_t w11 = pk_bf16(ph[8 * cl + 6], ph[8 * cl + 7]);
      plswap(w00, w10);
      plswap(w01, w11);
      u32x4 pw = {w00, w01, w10, w11};
      bf16x8 pf = __builtin_bit_cast(bf16x8, pw);
      {
        const int vrow = lq;
        bf16x8 vf = *reinterpret_cast<const bf16x8*>(
            &KVs[2 + cur][(vrow << 6) + (((c * 2 + hi) ^ (vrow & 7)) << 3)]);
        oacc0 = mfma32(vf, pf, oacc0);
      }
      {
        const int vrow = 32 + lq;
        bf16x8 vf = *reinterpret_cast<const bf16x8*>(
            &KVs[2 + cur][(vrow << 6) + (((c * 2 + hi) ^ (vrow & 7)) << 3)]);
        oacc1 = mfma32(vf, pf, oacc1);
      }
    }
    __syncthreads();
  }

  if constexpr (NSPLIT == 1) {
    // normalize + LDS transpose + coalesced bf16 store
    bf16_t* Os = &KVs[0][0] + w * 2048;
    const float inv = __builtin_amdgcn_rcpf(l_);
#pragma unroll
    for (int dh = 0; dh < 2; ++dh) {
      const f32x16 oa = dh ? oacc1 : oacc0;
#pragma unroll
      for (int g = 0; g < 8; ++g) {
        const int reg = g * 2;
        const int dl = (reg & 3) + 8 * (reg >> 2) + 4 * hi;
        const int d = dh * 32 + dl;
        const uint32_t wv = pk_bf16(oa[reg] * inv, oa[reg + 1] * inv);
        const int byte = lq * 128 + ((((d >> 3) ^ (lq & 7))) << 4) + ((d & 7) << 1);
        *reinterpret_cast<uint32_t*>(reinterpret_cast<char*>(Os) + byte) = wv;
      }
    }
#pragma unroll
    for (int it = 0; it < 4; ++it) {
      const int q = it * 8 + (lane >> 3);
      const int ch = lane & 7;
      bf16x8 ov = *reinterpret_cast<const bf16x8*>(
          reinterpret_cast<char*>(Os) + q * 128 + ((ch ^ (q & 7)) << 4));
      const size_t gaddr = (((size_t)(b * S_LEN + q0 + q)) << 10) + h * 64 + ch * 8;
      *reinterpret_cast<bf16x8*>(Og + gaddr) = ov;
    }
  } else {
    // fp32 unnormalized partial + (m,l); LDS transpose (f32, 16B-chunk swizzle)
    float* Os32 = reinterpret_cast<float*>(&KVs[0][0]) + w * 2048;  // 8KB/warp
#pragma unroll
    for (int dh = 0; dh < 2; ++dh) {
      const f32x16 oa = dh ? oacc1 : oacc0;
#pragma unroll
      for (int reg = 0; reg < 16; ++reg) {
        const int dl = (reg & 3) + 8 * (reg >> 2) + 4 * hi;
        const int d = dh * 32 + dl;
        Os32[lq * 64 + (((d >> 2) ^ (lq & 15)) << 2) + (d & 3)] = oa[reg];
      }
    }
    if (lane < 32) {
      float2 mlv; mlv.x = m_; mlv.y = l_;
      *reinterpret_cast<float2*>(Ml + (((size_t)(z * 32 + bh) * 2048 + q0 + lq) << 1)) = mlv;
    }
#pragma unroll
    for (int it = 0; it < 4; ++it) {
      const int q = it * 8 + (lane >> 3);
      const size_t rowoff = ((size_t)((z * 32 + bh) * 2048 + q0 + q)) << 6;
#pragma unroll
      for (int c2 = 0; c2 < 2; ++c2) {
        const int ch = ((lane & 7) << 1) + c2;
        f32x4 v = *reinterpret_cast<const f32x4*>(Os32 + q * 64 + ((ch ^ (q & 15)) << 2));
        *reinterpret_cast<f32x4*>(Op + rowoff + (ch << 2)) = v;
      }
    }
  }
#undef STAGE
}

// ---------------- combine two KV-half partials -> bf16 Ob ----------------
__global__ void attn_combine(const float* __restrict__ Op, const float* __restrict__ Ml,
                             bf16_t* __restrict__ Ob) {
  const int gid = blockIdx.x * 256 + threadIdx.x;   // 65536 rows x 16 chunks
  const int row = gid >> 4, ch = gid & 15;
  const float* o1 = Op + ((size_t)row << 6) + ch * 4;
  const float* o2 = o1 + (1u << 22);
  const float2 a1 = *reinterpret_cast<const float2*>(Ml + row * 2);
  const float2 a2 = *reinterpret_cast<const float2*>(Ml + (1u << 17) + row * 2);
  const float mmax = fmaxf(a1.x, a2.x);
  const float w1 = __builtin_amdgcn_exp2f(a1.x - mmax);
  const float w2 = __builtin_amdgcn_exp2f(a2.x - mmax);
  const float inv = 1.f / (a1.y * w1 + a2.y * w2);
  f32x4 v1 = *reinterpret_cast<const f32x4*>(o1);
  f32x4 v2 = *reinterpret_cast<const f32x4*>(o2);
  bf16x4 o;
#pragma unroll
  for (int i = 0; i < 4; ++i) o[i] = (bf16_t)((v1[i] * w1 + v2[i] * w2) * inv);
  const int bh = row >> 11, s = row & 2047;
  const int b = bh >> 4, h = bh & 15;
  *reinterpret_cast<bf16x4*>(Ob + (((size_t)(b * S_LEN + s)) << 10) + h * 64 + ch * 4) = o;
}

// ---------------------------------------------------------------------------
extern "C" void kernel_launch(void* const* d_in, const int* in_sizes, int n_in,
                              void* d_out, int out_size, void* d_ws, size_t ws_size,
                              hipStream_t stream) {
  const float* x = (const float*)d_in[0];
  const float* Wq = (const float*)d_in[1];
  const float* bq = (const float*)d_in[2];
  const float* Wk = (const float*)d_in[3];
  const float* bk = (const float*)d_in[4];
  const float* Wv = (const float*)d_in[5];
  const float* bv = (const float*)d_in[6];
  const float* Wo = (const float*)d_in[7];
  const float* bo = (const float*)d_in[8];
  const float* qnw = (const float*)d_in[9];
  const float* qnb = (const float*)d_in[10];
  const float* knw = (const float*)d_in[11];
  const float* knb = (const float*)d_in[12];
  float* out = (float*)d_out;

  uint8_t* ws = (uint8_t*)d_ws;
  bf16_t* xb = (bf16_t*)(ws + 0);          // [4096][1024]      8388608
  bf16_t* Wb = (bf16_t*)(ws + 8388608);    // [3072][1024]      6291456
  bf16_t* Wob = (bf16_t*)(ws + 14680064);  // [1024][1024]      2097152
  bf16_t* Qb = (bf16_t*)(ws + 16777216);   // [32][2048][64]    8388608
  bf16_t* Kb = (bf16_t*)(ws + 25165824);   // [32][2048][64]    8388608
  bf16_t* Vt = (bf16_t*)(ws + 33554432);   // [32][64][2048]    8388608
  bf16_t* Ob = (bf16_t*)(ws + 41943040);   // [4096][1024]      8388608
  float*  Opart = (float*)(ws + 50331648); // [2][65536][64]f32 33554432
  float*  Mlp   = (float*)(ws + 83886080); // [2][65536][2] f32  1048576
  const bool split = ws_size >= 84934656ull;

  cvt_all<<<8192, 256, 0, stream>>>(x, Wq, Wk, Wv, Wo, xb, Wb, Wob);

  gemm_qkv_ln<<<dim3(24, 32), 256, 0, stream>>>(xb, Wb, bq, bk, bv, qnw, qnb, knw, knb,
                                                Qb, Kb, Vt);
  if (split) {
    attn_kernel<2><<<dim3(16, 32, 2), 256, 0, stream>>>(Qb, Kb, Vt, Ob, Opart, Mlp);
    attn_combine<<<4096, 256, 0, stream>>>(Opart, Mlp, Ob);
  } else {
    attn_kernel<1><<<dim3(16, 32, 1), 256, 0, stream>>>(Qb, Kb, Vt, Ob, Opart, Mlp);
  }
  gemm_out<<<dim3(8, 64), 256, 0, stream>>>(Ob, Wob, bo, out);
}

// Round 4
// 122.271 us; speedup vs baseline: 1.6884x; 1.0765x over previous
//
#include <hip/hip_runtime.h>
#include <stdint.h>

// ---------------------------------------------------------------------------
// Fused MHA forward: B=2, S=2048, E=1024, H=16, D=64, fp32 in/out,
// bf16 MFMA compute internally. Exact (max-free) softmax: Q,K are LayerNorm'd
// so |score|*log2e <= ~23 -> exp2 never overflows; softmax is shift-invariant.
// ---------------------------------------------------------------------------

typedef __bf16 bf16_t;
typedef __bf16 bf16x8 __attribute__((ext_vector_type(8)));
typedef __bf16 bf16x4 __attribute__((ext_vector_type(4)));
typedef __bf16 bf16x2 __attribute__((ext_vector_type(2)));
typedef float f32x4 __attribute__((ext_vector_type(4)));
typedef float f32x16 __attribute__((ext_vector_type(16)));
typedef uint32_t u32x4 __attribute__((ext_vector_type(4)));

#define S_LEN 2048
#define QSCALE 0.1803368801f   // 0.125 * log2(e), folded into Q at GEMM1

__device__ __forceinline__ void load_lds16(const void* g, void* l) {
  __builtin_amdgcn_global_load_lds((__attribute__((address_space(1))) void*)g,
                                   (__attribute__((address_space(3))) void*)l,
                                   16, 0, 0);
}

__device__ __forceinline__ f32x4 mfma16(bf16x8 a, bf16x8 b, f32x4 c) {
  return __builtin_amdgcn_mfma_f32_16x16x32_bf16(a, b, c, 0, 0, 0);
}

__device__ __forceinline__ f32x16 mfma32(bf16x8 a, bf16x8 b, f32x16 c) {
  return __builtin_amdgcn_mfma_f32_32x32x16_bf16(a, b, c, 0, 0, 0);
}

__device__ __forceinline__ uint32_t pk_bf16(float a, float b) {
  bf16x2 v; v[0] = (bf16_t)a; v[1] = (bf16_t)b;
  return __builtin_bit_cast(uint32_t, v);
}

__device__ __forceinline__ void plswap(uint32_t& a, uint32_t& b) {
  asm volatile("v_permlane32_swap_b32 %0, %1" : "+v"(a), "+v"(b));
}

// ---------------- fp32 -> bf16 convert, all tensors in one launch ----------
__global__ void cvt_all(const float* __restrict__ x, const float* __restrict__ Wq,
                        const float* __restrict__ Wk, const float* __restrict__ Wv,
                        const float* __restrict__ Wo,
                        bf16_t* __restrict__ xb, bf16_t* __restrict__ Wb,
                        bf16_t* __restrict__ Wob) {
  const int bid = blockIdx.x;
  const float* src; bf16_t* dst; int idx;
  if (bid < 4096) { src = x; dst = xb; idx = bid; }
  else {
    const int r = bid - 4096, rg = r >> 10;
    idx = r & 1023;
    if (rg == 0)      { src = Wq; dst = Wb; }
    else if (rg == 1) { src = Wk; dst = Wb + (1 << 20); }
    else if (rg == 2) { src = Wv; dst = Wb + (2 << 20); }
    else              { src = Wo; dst = Wob; }
  }
  const int i = (idx * 256 + threadIdx.x) * 4;
  float4 v = *reinterpret_cast<const float4*>(src + i);
  bf16x4 o;
  o[0] = (bf16_t)v.x; o[1] = (bf16_t)v.y; o[2] = (bf16_t)v.z; o[3] = (bf16_t)v.w;
  *reinterpret_cast<bf16x4*>(dst + i) = o;
}

// ---------------- common 128x128 / BK=32 GEMM core (K=1024) ----------------
__device__ __forceinline__ void gemm_main(const bf16_t* __restrict__ ga,
                                          const bf16_t* __restrict__ gb,
                                          bf16_t* As, bf16_t* Bs,
                                          int t, int wr, int wc, int lg, int lr,
                                          f32x4 (&acc)[4][4]) {
  for (int k0 = 0; k0 < 1024; k0 += 32) {
    load_lds16(ga + k0,          As + t * 8);
    load_lds16(ga + 65536 + k0,  As + 2048 + t * 8);
    load_lds16(gb + k0,          Bs + t * 8);
    load_lds16(gb + 65536 + k0,  Bs + 2048 + t * 8);
    __syncthreads();
    bf16x8 af[4], bfr[4];
#pragma unroll
    for (int mt = 0; mt < 4; ++mt)
      af[mt] = *reinterpret_cast<const bf16x8*>(As + ((wr * 64 + mt * 16 + lr) << 5) + lg * 8);
#pragma unroll
    for (int nt = 0; nt < 4; ++nt)
      bfr[nt] = *reinterpret_cast<const bf16x8*>(Bs + ((wc * 64 + nt * 16 + lr) << 5) + lg * 8);
#pragma unroll
    for (int mt = 0; mt < 4; ++mt)
#pragma unroll
      for (int nt = 0; nt < 4; ++nt)
        acc[mt][nt] = mfma16(af[mt], bfr[nt], acc[mt][nt]);
    __syncthreads();
  }
}

// ---------------- GEMM1: QKV projection + bias + per-head LN ----------------
// Q additionally scaled by QSCALE (score scale * log2e) for max-free softmax.
__launch_bounds__(256, 2)
__global__ void gemm_qkv_ln(const bf16_t* __restrict__ A, const bf16_t* __restrict__ Bt,
                            const float* __restrict__ bq, const float* __restrict__ bk,
                            const float* __restrict__ bv,
                            const float* __restrict__ qnw, const float* __restrict__ qnb,
                            const float* __restrict__ knw, const float* __restrict__ knb,
                            bf16_t* __restrict__ Qb, bf16_t* __restrict__ Kb,
                            bf16_t* __restrict__ Vt) {
  __shared__ alignas(16) bf16_t As[128 * 32];
  __shared__ alignas(16) bf16_t Bs[128 * 32];
  const int t = threadIdx.x;
  const int orig = blockIdx.y * 24 + blockIdx.x;          // 768 blocks
  const int logical = (orig & 7) * 96 + (orig >> 3);      // XCD-contiguous
  const int bn = logical % 24, bm = logical / 24;
  const int w = t >> 6, lane = t & 63;
  const int wr = w >> 1, wc = w & 1;
  const int lg = lane >> 4, lr = lane & 15;

  f32x4 acc[4][4] = {};
  const int srow = t >> 2;
  const int scol = (t & 3) << 3;
  const bf16_t* ga = A + ((size_t)(bm * 128 + srow) << 10) + scol;
  const bf16_t* gb = Bt + ((size_t)(bn * 128 + srow) << 10) + scol;
  gemm_main(ga, gb, As, Bs, t, wr, wc, lg, lr, acc);

  const int nbase = bn * 128 + wc * 64;
  const int region = nbase >> 10;         // 0=Q 1=K 2=V
  const int h = (nbase & 1023) >> 6;

  if (region == 2) {
#pragma unroll
    for (int mt = 0; mt < 4; ++mt)
#pragma unroll
      for (int r = 0; r < 4; ++r) {
        const int gm = bm * 128 + wr * 64 + mt * 16 + lg * 4 + r;
        const int b = gm >> 11, s = gm & 2047;
#pragma unroll
        for (int nt = 0; nt < 4; ++nt) {
          const int d = nt * 16 + lr;
          float val = acc[mt][nt][r] + bv[h * 64 + d];
          Vt[((size_t)((b * 16 + h) * 64 + d) << 11) + s] = (bf16_t)val;
        }
      }
  } else {
    const float* bias = region ? bk : bq;
    const float* lw = region ? knw : qnw;
    const float* lb = region ? knb : qnb;
    const float osc = region ? 1.0f : QSCALE;
    bf16_t* Outp = region ? Kb : Qb;
#pragma unroll
    for (int mt = 0; mt < 4; ++mt)
#pragma unroll
      for (int r = 0; r < 4; ++r) {
        const int gm = bm * 128 + wr * 64 + mt * 16 + lg * 4 + r;
        const int b = gm >> 11, s = gm & 2047;
        float vv[4], sum = 0.f, sumsq = 0.f;
#pragma unroll
        for (int nt = 0; nt < 4; ++nt) {
          const int d = nt * 16 + lr;
          vv[nt] = acc[mt][nt][r] + bias[h * 64 + d];
          sum += vv[nt];
          sumsq += vv[nt] * vv[nt];
        }
#pragma unroll
        for (int mk = 1; mk < 16; mk <<= 1) {
          sum += __shfl_xor(sum, mk);
          sumsq += __shfl_xor(sumsq, mk);
        }
        const float mean = sum * (1.f / 64.f);
        const float var = sumsq * (1.f / 64.f) - mean * mean;
        const float rstd = rsqrtf(var + 1e-5f);
        const size_t rowoff = ((size_t)((b * 16 + h) * 2048 + s)) << 6;
#pragma unroll
        for (int nt = 0; nt < 4; ++nt) {
          const int d = nt * 16 + lr;
          float y = ((vv[nt] - mean) * rstd * lw[d] + lb[d]) * osc;
          Outp[rowoff + d] = (bf16_t)y;
        }
      }
  }
}

// ---------------- GEMM2: output projection, 64x128 tile -> 512 blocks -------
__launch_bounds__(256, 2)
__global__ void gemm_out(const bf16_t* __restrict__ A, const bf16_t* __restrict__ Bt,
                         const float* __restrict__ bo, float* __restrict__ dout) {
  __shared__ alignas(16) bf16_t As[64 * 32];
  __shared__ alignas(16) bf16_t Bs[128 * 32];
  const int t = threadIdx.x;
  const int orig = blockIdx.y * 8 + blockIdx.x;           // 512 blocks
  const int logical = (orig & 7) * 64 + (orig >> 3);
  const int bn = logical & 7, bm = logical >> 3;
  const int w = t >> 6, lane = t & 63;
  const int wr = w >> 1, wc = w & 1;
  const int lg = lane >> 4, lr = lane & 15;

  f32x4 acc[2][4] = {};
  const int srow = t >> 2;
  const int scol = (t & 3) << 3;
  const bf16_t* ga = A + ((size_t)(bm * 64 + srow) << 10) + scol;
  const bf16_t* gb = Bt + ((size_t)(bn * 128 + srow) << 10) + scol;

  for (int k0 = 0; k0 < 1024; k0 += 32) {
    load_lds16(ga + k0,          As + t * 8);
    load_lds16(gb + k0,          Bs + t * 8);
    load_lds16(gb + 65536 + k0,  Bs + 2048 + t * 8);
    __syncthreads();
    bf16x8 af[2], bfr[4];
#pragma unroll
    for (int mt = 0; mt < 2; ++mt)
      af[mt] = *reinterpret_cast<const bf16x8*>(As + ((wr * 32 + mt * 16 + lr) << 5) + lg * 8);
#pragma unroll
    for (int nt = 0; nt < 4; ++nt)
      bfr[nt] = *reinterpret_cast<const bf16x8*>(Bs + ((wc * 64 + nt * 16 + lr) << 5) + lg * 8);
#pragma unroll
    for (int mt = 0; mt < 2; ++mt)
#pragma unroll
      for (int nt = 0; nt < 4; ++nt)
        acc[mt][nt] = mfma16(af[mt], bfr[nt], acc[mt][nt]);
    __syncthreads();
  }

#pragma unroll
  for (int mt = 0; mt < 2; ++mt)
#pragma unroll
    for (int r = 0; r < 4; ++r) {
      const int gm = bm * 64 + wr * 32 + mt * 16 + lg * 4 + r;
#pragma unroll
      for (int nt = 0; nt < 4; ++nt) {
        const int gn = bn * 128 + wc * 64 + nt * 16 + lr;
        dout[((size_t)gm << 10) + gn] = acc[mt][nt][r] + bo[gn];
      }
    }
}

// ---------------- flash attention, max-free softmax ----------
// Block: 4 waves x 32 q = 128 q. Grid (16, 32, NSPLIT), XCD-swizzled.
// LDS tile layout (8KB, conflict-free): elem(row, ch8) =
//   (ch8>>1)*1024 + row*16 + (ch8&1)*8   [row = key for K / d for V; ch8 = 8-elem chunk]
// -> QK/PV wave reads are contiguous 1024B (zero bank conflicts).
// Staged via global_load_lds with the permutation applied on the global source.
template <int NSPLIT>
__launch_bounds__(256, 4)
__global__ void attn_kernel(const bf16_t* __restrict__ Qb, const bf16_t* __restrict__ Kb,
                            const bf16_t* __restrict__ Vt, bf16_t* __restrict__ Og,
                            float* __restrict__ Op, float* __restrict__ Lp) {
  __shared__ alignas(16) bf16_t KVs[4][64 * 64];  // [0..1]=K dbuf, [2..3]=V dbuf

  const int t = threadIdx.x;
  const int w = t >> 6, lane = t & 63;
  const int lq = lane & 31;
  const int hi = lane >> 5;
  const int orig = (blockIdx.z * 32 + blockIdx.y) * 16 + blockIdx.x;
  const int logical = (orig & 7) * (64 * NSPLIT) + (orig >> 3);  // XCD-contig
  const int qt = logical & 15;
  const int bh = (logical >> 4) & 31;
  const int z = (NSPLIT == 1) ? 0 : (logical >> 9);
  const int b = bh >> 4, h = bh & 15;
  const int q0 = qt * 128 + w * 32;
  const int ntiles = 32 / NSPLIT;

  bf16x8 qf[4];   // Q pre-scaled by QSCALE in GEMM1
  {
    const bf16_t* qp = Qb + (((size_t)bh * S_LEN + q0 + lq) << 6) + hi * 8;
#pragma unroll
    for (int c = 0; c < 4; ++c)
      qf[c] = *reinterpret_cast<const bf16x8*>(qp + c * 16);
  }

  f32x16 oacc0 = {}, oacc1 = {}, lacc = {};

  // staging decode: thread t -> LDS byte t*16 (linear dest); source element:
  const int krow = (t >> 1) & 63;
  const int kch = ((t >> 7) << 1) | (t & 1);
  const bf16_t* kbase = Kb + (((size_t)bh * S_LEN) << 6) + krow * 64 + kch * 8;
  const bf16_t* vbase = Vt + ((size_t)bh << 17) + krow * S_LEN + kch * 8;

#define STAGE(buf, jt)                                                       \
  {                                                                          \
    const bf16_t* kb_ = kbase + (((size_t)(jt)) << 12);                      \
    const bf16_t* vb_ = vbase + (jt) * 64;                                   \
    load_lds16(kb_,      &KVs[buf][t * 8]);                                  \
    load_lds16(kb_ + 32, &KVs[buf][2048 + t * 8]);                           \
    load_lds16(vb_,      &KVs[2 + (buf)][t * 8]);                            \
    load_lds16(vb_ + 32, &KVs[2 + (buf)][2048 + t * 8]);                     \
  }

  STAGE(0, z * ntiles);
  __syncthreads();

  for (int j = 0; j < ntiles; ++j) {
    const int cur = j & 1;
    if (j < ntiles - 1) STAGE(cur ^ 1, z * ntiles + j + 1);

    // ---- QK^T: S[key][q] (pre-scaled, log2 domain)
    f32x16 s0 = {}, s1 = {};
    const bf16_t* kr = &KVs[cur][lq * 16 + hi * 8];
#pragma unroll
    for (int c = 0; c < 4; ++c) {
      bf16x8 kf = *reinterpret_cast<const bf16x8*>(kr + c * 1024);
      s0 = mfma32(kf, qf[c], s0);
    }
#pragma unroll
    for (int c = 0; c < 4; ++c) {
      bf16x8 kf = *reinterpret_cast<const bf16x8*>(kr + 512 + c * 1024);
      s1 = mfma32(kf, qf[c], s1);
    }

    // ---- exact softmax numerator: p = exp2(s), no max needed (LN-bounded)
    f32x16 p0, p1;
#pragma unroll
    for (int i = 0; i < 16; ++i) p0[i] = __builtin_amdgcn_exp2f(s0[i]);
#pragma unroll
    for (int i = 0; i < 16; ++i) p1[i] = __builtin_amdgcn_exp2f(s1[i]);
    lacc += p0;
    lacc += p1;

    // ---- PV: O[d][q] += V^T · P^T
    const bf16_t* vr = &KVs[2 + cur][lq * 16 + hi * 8];
#pragma unroll
    for (int c = 0; c < 4; ++c) {
      const f32x16 ph = (c < 2) ? p0 : p1;
      const int cl = c & 1;
      uint32_t w00 = pk_bf16(ph[8 * cl + 0], ph[8 * cl + 1]);
      uint32_t w01 = pk_bf16(ph[8 * cl + 2], ph[8 * cl + 3]);
      uint32_t w10 = pk_bf16(ph[8 * cl + 4], ph[8 * cl + 5]);
      uint32_t w11 = pk_bf16(ph[8 * cl + 6], ph[8 * cl + 7]);
      plswap(w00, w10);
      plswap(w01, w11);
      u32x4 pw = {w00, w01, w10, w11};
      bf16x8 pf = __builtin_bit_cast(bf16x8, pw);
      {
        bf16x8 vf = *reinterpret_cast<const bf16x8*>(vr + c * 1024);
        oacc0 = mfma32(vf, pf, oacc0);
      }
      {
        bf16x8 vf = *reinterpret_cast<const bf16x8*>(vr + 512 + c * 1024);
        oacc1 = mfma32(vf, pf, oacc1);
      }
    }
    __syncthreads();
  }

  // ---- final l reduction: sum 16 regs + hi-partner lane
  float l_;
  {
    float sv[8];
#pragma unroll
    for (int i = 0; i < 8; ++i) sv[i] = lacc[i] + lacc[i + 8];
#pragma unroll
    for (int s2 = 4; s2 >= 1; s2 >>= 1)
#pragma unroll
      for (int i = 0; i < s2; ++i) sv[i] += sv[i + s2];
    l_ = sv[0] + __shfl_xor(sv[0], 32);
  }

  if constexpr (NSPLIT == 1) {
    bf16_t* Os = &KVs[0][0] + w * 2048;
    const float inv = __builtin_amdgcn_rcpf(l_);
#pragma unroll
    for (int dh = 0; dh < 2; ++dh) {
      const f32x16 oa = dh ? oacc1 : oacc0;
#pragma unroll
      for (int g = 0; g < 8; ++g) {
        const int reg = g * 2;
        const int dl = (reg & 3) + 8 * (reg >> 2) + 4 * hi;
        const int d = dh * 32 + dl;
        const uint32_t wv = pk_bf16(oa[reg] * inv, oa[reg + 1] * inv);
        const int byte = lq * 128 + ((((d >> 3) ^ (lq & 7))) << 4) + ((d & 7) << 1);
        *reinterpret_cast<uint32_t*>(reinterpret_cast<char*>(Os) + byte) = wv;
      }
    }
#pragma unroll
    for (int it = 0; it < 4; ++it) {
      const int q = it * 8 + (lane >> 3);
      const int ch = lane & 7;
      bf16x8 ov = *reinterpret_cast<const bf16x8*>(
          reinterpret_cast<char*>(Os) + q * 128 + ((ch ^ (q & 7)) << 4));
      const size_t gaddr = (((size_t)(b * S_LEN + q0 + q)) << 10) + h * 64 + ch * 8;
      *reinterpret_cast<bf16x8*>(Og + gaddr) = ov;
    }
  } else {
    float* Os32 = reinterpret_cast<float*>(&KVs[0][0]) + w * 2048;
#pragma unroll
    for (int dh = 0; dh < 2; ++dh) {
      const f32x16 oa = dh ? oacc1 : oacc0;
#pragma unroll
      for (int reg = 0; reg < 16; ++reg) {
        const int dl = (reg & 3) + 8 * (reg >> 2) + 4 * hi;
        const int d = dh * 32 + dl;
        Os32[lq * 64 + (((d >> 2) ^ (lq & 15)) << 2) + (d & 3)] = oa[reg];
      }
    }
    if (lane < 32) Lp[(size_t)(z * 32 + bh) * 2048 + q0 + lq] = l_;
#pragma unroll
    for (int it = 0; it < 4; ++it) {
      const int q = it * 8 + (lane >> 3);
      const size_t rowoff = ((size_t)((z * 32 + bh) * 2048 + q0 + q)) << 6;
#pragma unroll
      for (int c2 = 0; c2 < 2; ++c2) {
        const int ch = ((lane & 7) << 1) + c2;
        f32x4 v = *reinterpret_cast<const f32x4*>(Os32 + q * 64 + ((ch ^ (q & 15)) << 2));
        *reinterpret_cast<f32x4*>(Op + rowoff + (ch << 2)) = v;
      }
    }
  }
#undef STAGE
}

// ---------------- combine two KV-half partials -> bf16 Ob ----------------
__global__ void attn_combine(const float* __restrict__ Op, const float* __restrict__ Lp,
                             bf16_t* __restrict__ Ob) {
  const int gid = blockIdx.x * 256 + threadIdx.x;   // 65536 rows x 16 chunks
  const int row = gid >> 4, ch = gid & 15;
  const float* o1 = Op + ((size_t)row << 6) + ch * 4;
  const float* o2 = o1 + (1u << 22);
  const float inv = 1.f / (Lp[row] + Lp[(1u << 16) + row]);
  f32x4 v1 = *reinterpret_cast<const f32x4*>(o1);
  f32x4 v2 = *reinterpret_cast<const f32x4*>(o2);
  bf16x4 o;
#pragma unroll
  for (int i = 0; i < 4; ++i) o[i] = (bf16_t)((v1[i] + v2[i]) * inv);
  const int bh = row >> 11, s = row & 2047;
  const int b = bh >> 4, h = bh & 15;
  *reinterpret_cast<bf16x4*>(Ob + (((size_t)(b * S_LEN + s)) << 10) + h * 64 + ch * 4) = o;
}

// ---------------------------------------------------------------------------
extern "C" void kernel_launch(void* const* d_in, const int* in_sizes, int n_in,
                              void* d_out, int out_size, void* d_ws, size_t ws_size,
                              hipStream_t stream) {
  const float* x = (const float*)d_in[0];
  const float* Wq = (const float*)d_in[1];
  const float* bq = (const float*)d_in[2];
  const float* Wk = (const float*)d_in[3];
  const float* bk = (const float*)d_in[4];
  const float* Wv = (const float*)d_in[5];
  const float* bv = (const float*)d_in[6];
  const float* Wo = (const float*)d_in[7];
  const float* bo = (const float*)d_in[8];
  const float* qnw = (const float*)d_in[9];
  const float* qnb = (const float*)d_in[10];
  const float* knw = (const float*)d_in[11];
  const float* knb = (const float*)d_in[12];
  float* out = (float*)d_out;

  uint8_t* ws = (uint8_t*)d_ws;
  bf16_t* xb = (bf16_t*)(ws + 0);          // [4096][1024]      8388608
  bf16_t* Wb = (bf16_t*)(ws + 8388608);    // [3072][1024]      6291456
  bf16_t* Wob = (bf16_t*)(ws + 14680064);  // [1024][1024]      2097152
  bf16_t* Qb = (bf16_t*)(ws + 16777216);   // [32][2048][64]    8388608
  bf16_t* Kb = (bf16_t*)(ws + 25165824);   // [32][2048][64]    8388608
  bf16_t* Vt = (bf16_t*)(ws + 33554432);   // [32][64][2048]    8388608
  bf16_t* Ob = (bf16_t*)(ws + 41943040);   // [4096][1024]      8388608
  float*  Opart = (float*)(ws + 50331648); // [2][65536][64]f32 33554432
  float*  Lpart = (float*)(ws + 83886080); // [2][65536]   f32    524288
  const bool split = ws_size >= 84934656ull;

  cvt_all<<<8192, 256, 0, stream>>>(x, Wq, Wk, Wv, Wo, xb, Wb, Wob);

  gemm_qkv_ln<<<dim3(24, 32), 256, 0, stream>>>(xb, Wb, bq, bk, bv, qnw, qnb, knw, knb,
                                                Qb, Kb, Vt);
  if (split) {
    attn_kernel<2><<<dim3(16, 32, 2), 256, 0, stream>>>(Qb, Kb, Vt, Ob, Opart, Lpart);
    attn_combine<<<4096, 256, 0, stream>>>(Opart, Lpart, Ob);
  } else {
    attn_kernel<1><<<dim3(16, 32, 1), 256, 0, stream>>>(Qb, Kb, Vt, Ob, Opart, Lpart);
  }
  gemm_out<<<dim3(8, 64), 256, 0, stream>>>(Ob, Wob, bo, out);
}

// Round 5
// 117.715 us; speedup vs baseline: 1.7538x; 1.0387x over previous
//
#include <hip/hip_runtime.h>
#include <stdint.h>

// ---------------------------------------------------------------------------
// Fused MHA forward: B=2, S=2048, E=1024, H=16, D=64, fp32 in/out,
// bf16 MFMA compute internally. Exact (max-free) softmax: Q,K are LayerNorm'd
// so |score|*log2e <= ~23 -> exp2 never overflows; softmax is shift-invariant.
// GEMMs: 2-phase double-buffered LDS pipeline (stage k+1 before compute k).
// ---------------------------------------------------------------------------

typedef __bf16 bf16_t;
typedef __bf16 bf16x8 __attribute__((ext_vector_type(8)));
typedef __bf16 bf16x4 __attribute__((ext_vector_type(4)));
typedef __bf16 bf16x2 __attribute__((ext_vector_type(2)));
typedef float f32x4 __attribute__((ext_vector_type(4)));
typedef float f32x16 __attribute__((ext_vector_type(16)));
typedef uint32_t u32x4 __attribute__((ext_vector_type(4)));

#define S_LEN 2048
#define QSCALE 0.1803368801f   // 0.125 * log2(e), folded into Q at GEMM1

__device__ __forceinline__ void load_lds16(const void* g, void* l) {
  __builtin_amdgcn_global_load_lds((__attribute__((address_space(1))) void*)g,
                                   (__attribute__((address_space(3))) void*)l,
                                   16, 0, 0);
}

__device__ __forceinline__ f32x4 mfma16(bf16x8 a, bf16x8 b, f32x4 c) {
  return __builtin_amdgcn_mfma_f32_16x16x32_bf16(a, b, c, 0, 0, 0);
}

__device__ __forceinline__ f32x16 mfma32(bf16x8 a, bf16x8 b, f32x16 c) {
  return __builtin_amdgcn_mfma_f32_32x32x16_bf16(a, b, c, 0, 0, 0);
}

__device__ __forceinline__ uint32_t pk_bf16(float a, float b) {
  bf16x2 v; v[0] = (bf16_t)a; v[1] = (bf16_t)b;
  return __builtin_bit_cast(uint32_t, v);
}

__device__ __forceinline__ void plswap(uint32_t& a, uint32_t& b) {
  asm volatile("v_permlane32_swap_b32 %0, %1" : "+v"(a), "+v"(b));
}

// ---------------- fp32 -> bf16 convert, all tensors in one launch ----------
__global__ void cvt_all(const float* __restrict__ x, const float* __restrict__ Wq,
                        const float* __restrict__ Wk, const float* __restrict__ Wv,
                        const float* __restrict__ Wo,
                        bf16_t* __restrict__ xb, bf16_t* __restrict__ Wb,
                        bf16_t* __restrict__ Wob) {
  const int bid = blockIdx.x;
  const float* src; bf16_t* dst; int idx;
  if (bid < 4096) { src = x; dst = xb; idx = bid; }
  else {
    const int r = bid - 4096, rg = r >> 10;
    idx = r & 1023;
    if (rg == 0)      { src = Wq; dst = Wb; }
    else if (rg == 1) { src = Wk; dst = Wb + (1 << 20); }
    else if (rg == 2) { src = Wv; dst = Wb + (2 << 20); }
    else              { src = Wo; dst = Wob; }
  }
  const int i = (idx * 256 + threadIdx.x) * 4;
  float4 v = *reinterpret_cast<const float4*>(src + i);
  bf16x4 o;
  o[0] = (bf16_t)v.x; o[1] = (bf16_t)v.y; o[2] = (bf16_t)v.z; o[3] = (bf16_t)v.w;
  *reinterpret_cast<bf16x4*>(dst + i) = o;
}

// ---------------- GEMM1: QKV projection + bias + per-head LN ----------------
// 128x128 tile, BK=32, 2-phase dbuf. Q pre-scaled by QSCALE.
__launch_bounds__(256, 2)
__global__ void gemm_qkv_ln(const bf16_t* __restrict__ A, const bf16_t* __restrict__ Bt,
                            const float* __restrict__ bq, const float* __restrict__ bk,
                            const float* __restrict__ bv,
                            const float* __restrict__ qnw, const float* __restrict__ qnb,
                            const float* __restrict__ knw, const float* __restrict__ knb,
                            bf16_t* __restrict__ Qb, bf16_t* __restrict__ Kb,
                            bf16_t* __restrict__ Vt) {
  __shared__ alignas(16) bf16_t As[2][128 * 32];
  __shared__ alignas(16) bf16_t Bs[2][128 * 32];
  const int t = threadIdx.x;
  const int orig = blockIdx.y * 24 + blockIdx.x;          // 768 blocks
  const int logical = (orig & 7) * 96 + (orig >> 3);      // XCD-contiguous
  const int bn = logical % 24, bm = logical / 24;
  const int w = t >> 6, lane = t & 63;
  const int wr = w >> 1, wc = w & 1;
  const int lg = lane >> 4, lr = lane & 15;

  f32x4 acc[4][4] = {};
  const int srow = t >> 2;
  const int scol = (t & 3) << 3;
  const bf16_t* ga = A + ((size_t)(bm * 128 + srow) << 10) + scol;
  const bf16_t* gb = Bt + ((size_t)(bn * 128 + srow) << 10) + scol;

#define GSTAGE(buf, k0)                                        \
  {                                                            \
    load_lds16(ga + (k0),         &As[buf][t * 8]);            \
    load_lds16(ga + 65536 + (k0), &As[buf][2048 + t * 8]);     \
    load_lds16(gb + (k0),         &Bs[buf][t * 8]);            \
    load_lds16(gb + 65536 + (k0), &Bs[buf][2048 + t * 8]);     \
  }

  GSTAGE(0, 0);
  __syncthreads();
  for (int it = 0; it < 32; ++it) {
    const int cur = it & 1;
    if (it < 31) GSTAGE(cur ^ 1, (it + 1) << 5);
    bf16x8 af[4], bfr[4];
#pragma unroll
    for (int mt = 0; mt < 4; ++mt)
      af[mt] = *reinterpret_cast<const bf16x8*>(&As[cur][((wr * 64 + mt * 16 + lr) << 5) + lg * 8]);
#pragma unroll
    for (int nt = 0; nt < 4; ++nt)
      bfr[nt] = *reinterpret_cast<const bf16x8*>(&Bs[cur][((wc * 64 + nt * 16 + lr) << 5) + lg * 8]);
#pragma unroll
    for (int mt = 0; mt < 4; ++mt)
#pragma unroll
      for (int nt = 0; nt < 4; ++nt)
        acc[mt][nt] = mfma16(af[mt], bfr[nt], acc[mt][nt]);
    __syncthreads();
  }
#undef GSTAGE

  const int nbase = bn * 128 + wc * 64;
  const int region = nbase >> 10;         // 0=Q 1=K 2=V
  const int h = (nbase & 1023) >> 6;

  if (region == 2) {
#pragma unroll
    for (int mt = 0; mt < 4; ++mt)
#pragma unroll
      for (int r = 0; r < 4; ++r) {
        const int gm = bm * 128 + wr * 64 + mt * 16 + lg * 4 + r;
        const int b = gm >> 11, s = gm & 2047;
#pragma unroll
        for (int nt = 0; nt < 4; ++nt) {
          const int d = nt * 16 + lr;
          float val = acc[mt][nt][r] + bv[h * 64 + d];
          Vt[((size_t)((b * 16 + h) * 64 + d) << 11) + s] = (bf16_t)val;
        }
      }
  } else {
    const float* bias = region ? bk : bq;
    const float* lw = region ? knw : qnw;
    const float* lb = region ? knb : qnb;
    const float osc = region ? 1.0f : QSCALE;
    bf16_t* Outp = region ? Kb : Qb;
#pragma unroll
    for (int mt = 0; mt < 4; ++mt)
#pragma unroll
      for (int r = 0; r < 4; ++r) {
        const int gm = bm * 128 + wr * 64 + mt * 16 + lg * 4 + r;
        const int b = gm >> 11, s = gm & 2047;
        float vv[4], sum = 0.f, sumsq = 0.f;
#pragma unroll
        for (int nt = 0; nt < 4; ++nt) {
          const int d = nt * 16 + lr;
          vv[nt] = acc[mt][nt][r] + bias[h * 64 + d];
          sum += vv[nt];
          sumsq += vv[nt] * vv[nt];
        }
#pragma unroll
        for (int mk = 1; mk < 16; mk <<= 1) {
          sum += __shfl_xor(sum, mk);
          sumsq += __shfl_xor(sumsq, mk);
        }
        const float mean = sum * (1.f / 64.f);
        const float var = sumsq * (1.f / 64.f) - mean * mean;
        const float rstd = rsqrtf(var + 1e-5f);
        const size_t rowoff = ((size_t)((b * 16 + h) * 2048 + s)) << 6;
#pragma unroll
        for (int nt = 0; nt < 4; ++nt) {
          const int d = nt * 16 + lr;
          float y = ((vv[nt] - mean) * rstd * lw[d] + lb[d]) * osc;
          Outp[rowoff + d] = (bf16_t)y;
        }
      }
  }
}

// ---------------- GEMM2: output projection, 64x128 tile, 2-phase dbuf -------
__launch_bounds__(256, 2)
__global__ void gemm_out(const bf16_t* __restrict__ A, const bf16_t* __restrict__ Bt,
                         const float* __restrict__ bo, float* __restrict__ dout) {
  __shared__ alignas(16) bf16_t As[2][64 * 32];
  __shared__ alignas(16) bf16_t Bs[2][128 * 32];
  const int t = threadIdx.x;
  const int orig = blockIdx.y * 8 + blockIdx.x;           // 512 blocks
  const int logical = (orig & 7) * 64 + (orig >> 3);
  const int bn = logical & 7, bm = logical >> 3;
  const int w = t >> 6, lane = t & 63;
  const int wr = w >> 1, wc = w & 1;
  const int lg = lane >> 4, lr = lane & 15;

  f32x4 acc[2][4] = {};
  const int srow = t >> 2;
  const int scol = (t & 3) << 3;
  const bf16_t* ga = A + ((size_t)(bm * 64 + srow) << 10) + scol;
  const bf16_t* gb = Bt + ((size_t)(bn * 128 + srow) << 10) + scol;

#define OSTAGE(buf, k0)                                        \
  {                                                            \
    load_lds16(ga + (k0),         &As[buf][t * 8]);            \
    load_lds16(gb + (k0),         &Bs[buf][t * 8]);            \
    load_lds16(gb + 65536 + (k0), &Bs[buf][2048 + t * 8]);     \
  }

  OSTAGE(0, 0);
  __syncthreads();
  for (int it = 0; it < 32; ++it) {
    const int cur = it & 1;
    if (it < 31) OSTAGE(cur ^ 1, (it + 1) << 5);
    bf16x8 af[2], bfr[4];
#pragma unroll
    for (int mt = 0; mt < 2; ++mt)
      af[mt] = *reinterpret_cast<const bf16x8*>(&As[cur][((wr * 32 + mt * 16 + lr) << 5) + lg * 8]);
#pragma unroll
    for (int nt = 0; nt < 4; ++nt)
      bfr[nt] = *reinterpret_cast<const bf16x8*>(&Bs[cur][((wc * 64 + nt * 16 + lr) << 5) + lg * 8]);
#pragma unroll
    for (int mt = 0; mt < 2; ++mt)
#pragma unroll
      for (int nt = 0; nt < 4; ++nt)
        acc[mt][nt] = mfma16(af[mt], bfr[nt], acc[mt][nt]);
    __syncthreads();
  }
#undef OSTAGE

#pragma unroll
  for (int mt = 0; mt < 2; ++mt)
#pragma unroll
    for (int r = 0; r < 4; ++r) {
      const int gm = bm * 64 + wr * 32 + mt * 16 + lg * 4 + r;
#pragma unroll
      for (int nt = 0; nt < 4; ++nt) {
        const int gn = bn * 128 + wc * 64 + nt * 16 + lr;
        dout[((size_t)gm << 10) + gn] = acc[mt][nt][r] + bo[gn];
      }
    }
}

// ---------------- flash attention, max-free softmax ----------
// Block: 4 waves x 32 q = 128 q. Grid (16, 32, NSPLIT), XCD-swizzled.
// LDS tile layout (8KB, conflict-free): elem(row, ch8) =
//   (ch8>>1)*1024 + row*16 + (ch8&1)*8. Staged via global_load_lds with the
// permutation applied on the global source (linear LDS dest).
// NSPLIT=2: bf16 unnormalized partials + fp32 l.
template <int NSPLIT>
__launch_bounds__(256, 4)
__global__ void attn_kernel(const bf16_t* __restrict__ Qb, const bf16_t* __restrict__ Kb,
                            const bf16_t* __restrict__ Vt, bf16_t* __restrict__ Og,
                            bf16_t* __restrict__ Op, float* __restrict__ Lp) {
  __shared__ alignas(16) bf16_t KVs[4][64 * 64];  // [0..1]=K dbuf, [2..3]=V dbuf

  const int t = threadIdx.x;
  const int w = t >> 6, lane = t & 63;
  const int lq = lane & 31;
  const int hi = lane >> 5;
  const int orig = (blockIdx.z * 32 + blockIdx.y) * 16 + blockIdx.x;
  const int logical = (orig & 7) * (64 * NSPLIT) + (orig >> 3);  // XCD-contig
  const int qt = logical & 15;
  const int bh = (logical >> 4) & 31;
  const int z = (NSPLIT == 1) ? 0 : (logical >> 9);
  const int b = bh >> 4, h = bh & 15;
  const int q0 = qt * 128 + w * 32;
  const int ntiles = 32 / NSPLIT;

  bf16x8 qf[4];   // Q pre-scaled by QSCALE in GEMM1
  {
    const bf16_t* qp = Qb + (((size_t)bh * S_LEN + q0 + lq) << 6) + hi * 8;
#pragma unroll
    for (int c = 0; c < 4; ++c)
      qf[c] = *reinterpret_cast<const bf16x8*>(qp + c * 16);
  }

  f32x16 oacc0 = {}, oacc1 = {}, lacc = {};

  // staging decode: thread t -> LDS byte t*16 (linear dest); source element:
  const int krow = (t >> 1) & 63;
  const int kch = ((t >> 7) << 1) | (t & 1);
  const bf16_t* kbase = Kb + (((size_t)bh * S_LEN) << 6) + krow * 64 + kch * 8;
  const bf16_t* vbase = Vt + ((size_t)bh << 17) + krow * S_LEN + kch * 8;

#define STAGE(buf, jt)                                                       \
  {                                                                          \
    const bf16_t* kb_ = kbase + (((size_t)(jt)) << 12);                      \
    const bf16_t* vb_ = vbase + (jt) * 64;                                   \
    load_lds16(kb_,      &KVs[buf][t * 8]);                                  \
    load_lds16(kb_ + 32, &KVs[buf][2048 + t * 8]);                           \
    load_lds16(vb_,      &KVs[2 + (buf)][t * 8]);                            \
    load_lds16(vb_ + 32, &KVs[2 + (buf)][2048 + t * 8]);                     \
  }

  STAGE(0, z * ntiles);
  __syncthreads();

  for (int j = 0; j < ntiles; ++j) {
    const int cur = j & 1;
    if (j < ntiles - 1) STAGE(cur ^ 1, z * ntiles + j + 1);

    // ---- QK^T: S[key][q] (pre-scaled, log2 domain)
    f32x16 s0 = {}, s1 = {};
    const bf16_t* kr = &KVs[cur][lq * 16 + hi * 8];
#pragma unroll
    for (int c = 0; c < 4; ++c) {
      bf16x8 kf = *reinterpret_cast<const bf16x8*>(kr + c * 1024);
      s0 = mfma32(kf, qf[c], s0);
    }
#pragma unroll
    for (int c = 0; c < 4; ++c) {
      bf16x8 kf = *reinterpret_cast<const bf16x8*>(kr + 512 + c * 1024);
      s1 = mfma32(kf, qf[c], s1);
    }

    // ---- exact softmax numerator: p = exp2(s), no max needed (LN-bounded)
    f32x16 p0, p1;
#pragma unroll
    for (int i = 0; i < 16; ++i) p0[i] = __builtin_amdgcn_exp2f(s0[i]);
#pragma unroll
    for (int i = 0; i < 16; ++i) p1[i] = __builtin_amdgcn_exp2f(s1[i]);
    lacc += p0;
    lacc += p1;

    // ---- PV: O[d][q] += V^T · P^T
    const bf16_t* vr = &KVs[2 + cur][lq * 16 + hi * 8];
#pragma unroll
    for (int c = 0; c < 4; ++c) {
      const f32x16 ph = (c < 2) ? p0 : p1;
      const int cl = c & 1;
      uint32_t w00 = pk_bf16(ph[8 * cl + 0], ph[8 * cl + 1]);
      uint32_t w01 = pk_bf16(ph[8 * cl + 2], ph[8 * cl + 3]);
      uint32_t w10 = pk_bf16(ph[8 * cl + 4], ph[8 * cl + 5]);
      uint32_t w11 = pk_bf16(ph[8 * cl + 6], ph[8 * cl + 7]);
      plswap(w00, w10);
      plswap(w01, w11);
      u32x4 pw = {w00, w01, w10, w11};
      bf16x8 pf = __builtin_bit_cast(bf16x8, pw);
      {
        bf16x8 vf = *reinterpret_cast<const bf16x8*>(vr + c * 1024);
        oacc0 = mfma32(vf, pf, oacc0);
      }
      {
        bf16x8 vf = *reinterpret_cast<const bf16x8*>(vr + 512 + c * 1024);
        oacc1 = mfma32(vf, pf, oacc1);
      }
    }
    __syncthreads();
  }

  // ---- final l reduction: sum 16 regs + hi-partner lane
  float l_;
  {
    float sv[8];
#pragma unroll
    for (int i = 0; i < 8; ++i) sv[i] = lacc[i] + lacc[i + 8];
#pragma unroll
    for (int s2 = 4; s2 >= 1; s2 >>= 1)
#pragma unroll
      for (int i = 0; i < s2; ++i) sv[i] += sv[i + s2];
    l_ = sv[0] + __shfl_xor(sv[0], 32);
  }

  // ---- epilogue: (optionally normalized) bf16 transpose via LDS, 16B stores
  {
    bf16_t* Os = &KVs[0][0] + w * 2048;   // 4KB/warp inside K buffers
    const float inv = (NSPLIT == 1) ? __builtin_amdgcn_rcpf(l_) : 1.0f;
#pragma unroll
    for (int dh = 0; dh < 2; ++dh) {
      const f32x16 oa = dh ? oacc1 : oacc0;
#pragma unroll
      for (int g = 0; g < 8; ++g) {
        const int reg = g * 2;
        const int dl = (reg & 3) + 8 * (reg >> 2) + 4 * hi;
        const int d = dh * 32 + dl;
        const uint32_t wv = pk_bf16(oa[reg] * inv, oa[reg + 1] * inv);
        const int byte = lq * 128 + ((((d >> 3) ^ (lq & 7))) << 4) + ((d & 7) << 1);
        *reinterpret_cast<uint32_t*>(reinterpret_cast<char*>(Os) + byte) = wv;
      }
    }
    if (NSPLIT == 2 && lane < 32)
      Lp[(size_t)(z * 32 + bh) * 2048 + q0 + lq] = l_;
#pragma unroll
    for (int it = 0; it < 4; ++it) {
      const int q = it * 8 + (lane >> 3);
      const int ch = lane & 7;
      bf16x8 ov = *reinterpret_cast<const bf16x8*>(
          reinterpret_cast<char*>(Os) + q * 128 + ((ch ^ (q & 7)) << 4));
      if constexpr (NSPLIT == 1) {
        const size_t gaddr = (((size_t)(b * S_LEN + q0 + q)) << 10) + h * 64 + ch * 8;
        *reinterpret_cast<bf16x8*>(Og + gaddr) = ov;
      } else {
        const size_t rowoff = ((size_t)((z * 32 + bh) * 2048 + q0 + q)) << 6;
        *reinterpret_cast<bf16x8*>(Op + rowoff + ch * 8) = ov;
      }
    }
  }
#undef STAGE
}

// ---------------- combine two KV-half bf16 partials -> bf16 Ob ----------------
__global__ void attn_combine(const bf16_t* __restrict__ Op, const float* __restrict__ Lp,
                             bf16_t* __restrict__ Ob) {
  const int gid = blockIdx.x * 256 + threadIdx.x;   // 65536 rows x 8 chunks of 8
  const int row = gid >> 3, ch = gid & 7;
  const bf16_t* o1 = Op + ((size_t)row << 6) + ch * 8;
  const bf16_t* o2 = o1 + (1u << 22);               // + 65536*64 elems
  const float inv = 1.f / (Lp[row] + Lp[(1u << 16) + row]);
  bf16x8 v1 = *reinterpret_cast<const bf16x8*>(o1);
  bf16x8 v2 = *reinterpret_cast<const bf16x8*>(o2);
  bf16x8 o;
#pragma unroll
  for (int i = 0; i < 8; ++i) o[i] = (bf16_t)(((float)v1[i] + (float)v2[i]) * inv);
  const int bh = row >> 11, s = row & 2047;
  const int b = bh >> 4, h = bh & 15;
  *reinterpret_cast<bf16x8*>(Ob + (((size_t)(b * S_LEN + s)) << 10) + h * 64 + ch * 8) = o;
}

// ---------------------------------------------------------------------------
extern "C" void kernel_launch(void* const* d_in, const int* in_sizes, int n_in,
                              void* d_out, int out_size, void* d_ws, size_t ws_size,
                              hipStream_t stream) {
  const float* x = (const float*)d_in[0];
  const float* Wq = (const float*)d_in[1];
  const float* bq = (const float*)d_in[2];
  const float* Wk = (const float*)d_in[3];
  const float* bk = (const float*)d_in[4];
  const float* Wv = (const float*)d_in[5];
  const float* bv = (const float*)d_in[6];
  const float* Wo = (const float*)d_in[7];
  const float* bo = (const float*)d_in[8];
  const float* qnw = (const float*)d_in[9];
  const float* qnb = (const float*)d_in[10];
  const float* knw = (const float*)d_in[11];
  const float* knb = (const float*)d_in[12];
  float* out = (float*)d_out;

  uint8_t* ws = (uint8_t*)d_ws;
  bf16_t* xb = (bf16_t*)(ws + 0);          // [4096][1024]      8388608
  bf16_t* Wb = (bf16_t*)(ws + 8388608);    // [3072][1024]      6291456
  bf16_t* Wob = (bf16_t*)(ws + 14680064);  // [1024][1024]      2097152
  bf16_t* Qb = (bf16_t*)(ws + 16777216);   // [32][2048][64]    8388608
  bf16_t* Kb = (bf16_t*)(ws + 25165824);   // [32][2048][64]    8388608
  bf16_t* Vt = (bf16_t*)(ws + 33554432);   // [32][64][2048]    8388608
  bf16_t* Ob = (bf16_t*)(ws + 41943040);   // [4096][1024]      8388608
  bf16_t* Opart = (bf16_t*)(ws + 50331648);// [2][65536][64]bf16 16777216
  float*  Lpart = (float*)(ws + 67108864); // [2][65536]   f32     524288
  const bool split = ws_size >= 67633152ull;

  cvt_all<<<8192, 256, 0, stream>>>(x, Wq, Wk, Wv, Wo, xb, Wb, Wob);

  gemm_qkv_ln<<<dim3(24, 32), 256, 0, stream>>>(xb, Wb, bq, bk, bv, qnw, qnb, knw, knb,
                                                Qb, Kb, Vt);
  if (split) {
    attn_kernel<2><<<dim3(16, 32, 2), 256, 0, stream>>>(Qb, Kb, Vt, Ob, Opart, Lpart);
    attn_combine<<<2048, 256, 0, stream>>>(Opart, Lpart, Ob);
  } else {
    attn_kernel<1><<<dim3(16, 32, 1), 256, 0, stream>>>(Qb, Kb, Vt, Ob, Opart, Lpart);
  }
  gemm_out<<<dim3(8, 64), 256, 0, stream>>>(Ob, Wob, bo, out);
}